// Round 1
// baseline (656.260 us; speedup 1.0000x reference)
//
#include <hip/hip_runtime.h>
#include <cmath>

// Shapes (fixed for this problem)
#define B_    2
#define N_    6
#define D_    128
#define Q_    2304      // 48*48
#define K_    576       // 24*24
#define NK_   3456      // N_*K_
#define HEADS_ 4
#define DH_   32
#define SCALE_ 0.17677669529663687f  // 1/sqrt(32)

// ---------------------------------------------------------------------------
// Kernel A: LayerNorm + projection for q/k/v.
// x: (O, 128, S) strided layout (channel-major); out: (O, S, 128)
// Block: 256 threads, 32 spatial positions per block.
// ---------------------------------------------------------------------------
__global__ __launch_bounds__(256) void k_ln_proj(
    const float* __restrict__ x, const float* __restrict__ g,
    const float* __restrict__ bln, const float* __restrict__ Wm,
    const float* __restrict__ bias, float* __restrict__ out, int S)
{
  __shared__ float xs[32][132];     // [s][c], stride 132 keeps 16B alignment
  __shared__ float wsm[64][128];    // W chunk (c rows x j cols)
  __shared__ float gs[128], bs[128];
  __shared__ float mu[32], rsd[32];
  const int t = threadIdx.x;
  const int ntile = S >> 5;
  const int o  = blockIdx.x / ntile;
  const int s0 = (blockIdx.x % ntile) << 5;

  if (t < 128) { gs[t] = g[t]; bs[t] = bln[t]; }
  const float* xb = x + (size_t)o * 128 * (size_t)S + s0;
#pragma unroll
  for (int i = 0; i < 16; ++i) {
    int idx = t + 256 * i;          // 4096 elements
    int c = idx >> 5, s = idx & 31; // consecutive lanes -> consecutive s (coalesced)
    xs[s][c] = xb[(size_t)c * S + s];
  }
  __syncthreads();
  {   // LN stats: 8 lanes per position
    int s = t >> 3, l8 = t & 7;
    float sum = 0.f, sq = 0.f;
    for (int c = l8; c < 128; c += 8) { float v = xs[s][c]; sum += v; sq += v * v; }
#pragma unroll
    for (int off = 4; off > 0; off >>= 1) {
      sum += __shfl_down(sum, off, 8);
      sq  += __shfl_down(sq,  off, 8);
    }
    if (l8 == 0) {
      float m = sum * 0.0078125f;
      float var = sq * 0.0078125f - m * m;
      mu[s] = m; rsd[s] = rsqrtf(var + 1e-5f);
    }
  }
  __syncthreads();
#pragma unroll
  for (int i = 0; i < 16; ++i) {
    int idx = t + 256 * i;
    int c = idx & 127, s = idx >> 7;
    xs[s][c] = (xs[s][c] - mu[s]) * rsd[s] * gs[c] + bs[c];
  }
  // matmul 32x128 @ 128x128, register tile 4 rows x 4 cols per thread
  const int r0 = (t >> 5) << 2, j0 = (t & 31) << 2;
  float acc[4][4] = {};
  for (int cb = 0; cb < 2; ++cb) {
#pragma unroll
    for (int i = 0; i < 32; ++i) {
      int idx = t + 256 * i;        // 8192
      int c = idx >> 7, j = idx & 127;
      wsm[c][j] = Wm[(size_t)(cb * 64 + c) * 128 + j];
    }
    __syncthreads();                // also orders normalize-writes before reads
    for (int c = 0; c < 64; c += 4) {
      float4 w0 = *(const float4*)&wsm[c][j0];
      float4 w1 = *(const float4*)&wsm[c + 1][j0];
      float4 w2 = *(const float4*)&wsm[c + 2][j0];
      float4 w3 = *(const float4*)&wsm[c + 3][j0];
#pragma unroll
      for (int i = 0; i < 4; ++i) {
        float4 xv = *(const float4*)&xs[r0 + i][cb * 64 + c];
        acc[i][0] += xv.x*w0.x + xv.y*w1.x + xv.z*w2.x + xv.w*w3.x;
        acc[i][1] += xv.x*w0.y + xv.y*w1.y + xv.z*w2.y + xv.w*w3.y;
        acc[i][2] += xv.x*w0.z + xv.y*w1.z + xv.z*w2.z + xv.w*w3.z;
        acc[i][3] += xv.x*w0.w + xv.y*w1.w + xv.z*w2.w + xv.w*w3.w;
      }
    }
    __syncthreads();
  }
  float4 bv = *(const float4*)&bias[j0];
#pragma unroll
  for (int i = 0; i < 4; ++i) {
    float4 r;
    r.x = acc[i][0] + bv.x; r.y = acc[i][1] + bv.y;
    r.z = acc[i][2] + bv.z; r.w = acc[i][3] + bv.w;
    *(float4*)&out[((size_t)o * S + s0 + r0 + i) * 128 + j0] = r;
  }
}

// ---------------------------------------------------------------------------
// Kernel B: joint attention over (n,k) with online softmax.
// 16 queries per block; grid = (B*HEADS) * (Q/16) = 1152 blocks.
// ---------------------------------------------------------------------------
__device__ __forceinline__ float dot32(const float4* qv, const float4* kv) {
  float s = 0.f;
#pragma unroll
  for (int i = 0; i < 8; ++i)
    s += qv[i].x*kv[i].x + qv[i].y*kv[i].y + qv[i].z*kv[i].z + qv[i].w*kv[i].w;
  return s;
}

__global__ __launch_bounds__(256) void k_attn(
    const float* __restrict__ QP, const float* __restrict__ KP,
    const float* __restrict__ VP, float* __restrict__ AO)
{
  __shared__ float qs[6][16][32];   // q fragments per view
  __shared__ float sc[16][128];     // score chunk
  __shared__ float vs[128][32];     // V chunk
  __shared__ float mst[16], lst[16], alp[16];
  const int t  = threadIdx.x;
  const int qt = blockIdx.x % 144;
  const int bh = blockIdx.x / 144;
  const int bb = bh >> 2, h = bh & 3;
  const int q0 = qt << 4;

#pragma unroll
  for (int i = 0; i < 12; ++i) {
    int idx = t + 256 * i;          // 3072
    int n = idx >> 9, rem = idx & 511;
    int qi = rem >> 5, dd = rem & 31;
    qs[n][qi][dd] = QP[((size_t)(bb * 6 + n) * Q_ + q0 + qi) * 128 + h * DH_ + dd];
  }
  if (t < 16) { mst[t] = -INFINITY; lst[t] = 0.f; }
  const int qi_p = t >> 4;          // PV: q row owned by this thread
  const int dp   = (t & 15) << 1;   // PV: dim pair
  float o0 = 0.f, o1 = 0.f;
  __syncthreads();

  for (int kc = 0; kc < 27; ++kc) {
    // stage V chunk (independent of QK, no sync needed in between)
#pragma unroll
    for (int i = 0; i < 16; ++i) {
      int idx = t + 256 * i;        // 4096
      int kk = idx >> 5, dd = idx & 31;
      vs[kk][dd] = VP[((size_t)bb * NK_ + kc * 128 + kk) * 128 + h * DH_ + dd];
    }
    // QK: thread owns one K row (loaded to regs once) x 8 queries
    {
      int kk = t & 127, qh = (t >> 7) << 3;    // qh = 0 or 8
      int kg = kc * 128 + kk;
      int n  = kg / 576;
      const float4* kr = (const float4*)&KP[((size_t)(bb * 6 + n) * K_ + (kg - n * 576)) * 128 + h * DH_];
      float4 kv[8];
#pragma unroll
      for (int i = 0; i < 8; ++i) kv[i] = kr[i];
#pragma unroll
      for (int j = 0; j < 8; ++j) {
        const float4* qv = (const float4*)&qs[n][qh + j][0];
        sc[qh + j][kk] = dot32(qv, kv) * SCALE_;
      }
    }
    __syncthreads();
    // online softmax update: 16 lanes per q row
    {
      int qi = t >> 4, l16 = t & 15;
      float lm = -INFINITY;
#pragma unroll
      for (int kk = l16; kk < 128; kk += 16) lm = fmaxf(lm, sc[qi][kk]);
#pragma unroll
      for (int off = 8; off > 0; off >>= 1) lm = fmaxf(lm, __shfl_down(lm, off, 16));
      lm = __shfl(lm, 0, 16);
      float mold = mst[qi];
      float mnew = fmaxf(mold, lm);
      float a = __expf(mold - mnew);
      float ls = 0.f;
#pragma unroll
      for (int kk = l16; kk < 128; kk += 16) {
        float p = __expf(sc[qi][kk] - mnew);
        sc[qi][kk] = p;
        ls += p;
      }
#pragma unroll
      for (int off = 8; off > 0; off >>= 1) ls += __shfl_down(ls, off, 16);
      if (l16 == 0) {
        mst[qi] = mnew;
        lst[qi] = lst[qi] * a + ls;
        alp[qi] = a;
      }
    }
    __syncthreads();
    // PV accumulate
    {
      float a = alp[qi_p];
      o0 *= a; o1 *= a;
      for (int kk = 0; kk < 128; ++kk) {
        float p = sc[qi_p][kk];                    // broadcast within 16-lane group
        float2 v = *(const float2*)&vs[kk][dp];
        o0 += p * v.x; o1 += p * v.y;
      }
    }
    __syncthreads();
  }
  float inv = 1.f / lst[qi_p];
  float2 r; r.x = o0 * inv; r.y = o1 * inv;
  *(float2*)&AO[((size_t)bb * Q_ + q0 + qi_p) * 128 + h * DH_ + dp] = r;
}

// ---------------------------------------------------------------------------
// Kernel C: attention-out projection + bias + skip + pre-LN.
// AO rows contiguous (B*Q, 128); ZB out (B*Q, 128)
// ---------------------------------------------------------------------------
__global__ __launch_bounds__(256) void k_proj_skip_ln(
    const float* __restrict__ AO, const float* __restrict__ Wp,
    const float* __restrict__ bp, const float* __restrict__ skip,
    const float* __restrict__ g, const float* __restrict__ bln,
    float* __restrict__ ZB)
{
  __shared__ float xs[32][132];
  __shared__ float wsm[64][128];
  __shared__ float gs[128], bs[128];
  __shared__ float mu[32], rsd[32];
  const int t = threadIdx.x;
  const int row0 = blockIdx.x << 5;
  const int bb = row0 / Q_;
  const int hw0 = row0 % Q_;

  if (t < 128) { gs[t] = g[t]; bs[t] = bln[t]; }
#pragma unroll
  for (int i = 0; i < 16; ++i) {
    int idx = t + 256 * i;
    int c = idx & 127, s = idx >> 7;
    xs[s][c] = AO[(size_t)(row0 + s) * 128 + c];
  }
  const int r0 = (t >> 5) << 2, j0 = (t & 31) << 2;
  float acc[4][4] = {};
  for (int cb = 0; cb < 2; ++cb) {
#pragma unroll
    for (int i = 0; i < 32; ++i) {
      int idx = t + 256 * i;
      int c = idx >> 7, j = idx & 127;
      wsm[c][j] = Wp[(size_t)(cb * 64 + c) * 128 + j];
    }
    __syncthreads();
    for (int c = 0; c < 64; c += 4) {
      float4 w0 = *(const float4*)&wsm[c][j0];
      float4 w1 = *(const float4*)&wsm[c + 1][j0];
      float4 w2 = *(const float4*)&wsm[c + 2][j0];
      float4 w3 = *(const float4*)&wsm[c + 3][j0];
#pragma unroll
      for (int i = 0; i < 4; ++i) {
        float4 xv = *(const float4*)&xs[r0 + i][cb * 64 + c];
        acc[i][0] += xv.x*w0.x + xv.y*w1.x + xv.z*w2.x + xv.w*w3.x;
        acc[i][1] += xv.x*w0.y + xv.y*w1.y + xv.z*w2.y + xv.w*w3.y;
        acc[i][2] += xv.x*w0.z + xv.y*w1.z + xv.z*w2.z + xv.w*w3.z;
        acc[i][3] += xv.x*w0.w + xv.y*w1.w + xv.z*w2.w + xv.w*w3.w;
      }
    }
    __syncthreads();
  }
  float4 bv = *(const float4*)&bp[j0];
  float res[4][4];
#pragma unroll
  for (int i = 0; i < 4; ++i) {
    int hw = hw0 + r0 + i;
    res[i][0] = acc[i][0] + bv.x + skip[((size_t)bb * 128 + j0 + 0) * Q_ + hw];
    res[i][1] = acc[i][1] + bv.y + skip[((size_t)bb * 128 + j0 + 1) * Q_ + hw];
    res[i][2] = acc[i][2] + bv.z + skip[((size_t)bb * 128 + j0 + 2) * Q_ + hw];
    res[i][3] = acc[i][3] + bv.w + skip[((size_t)bb * 128 + j0 + 3) * Q_ + hw];
  }
  // xs no longer needed as input (cb loop ended with sync); reuse for y
#pragma unroll
  for (int i = 0; i < 4; ++i)
    *(float4*)&xs[r0 + i][j0] = make_float4(res[i][0], res[i][1], res[i][2], res[i][3]);
  __syncthreads();
  {
    int s = t >> 3, l8 = t & 7;
    float sum = 0.f, sq = 0.f;
    for (int c = l8; c < 128; c += 8) { float v = xs[s][c]; sum += v; sq += v * v; }
#pragma unroll
    for (int off = 4; off > 0; off >>= 1) {
      sum += __shfl_down(sum, off, 8);
      sq  += __shfl_down(sq,  off, 8);
    }
    if (l8 == 0) {
      float m = sum * 0.0078125f;
      float var = sq * 0.0078125f - m * m;
      mu[s] = m; rsd[s] = rsqrtf(var + 1e-5f);
    }
  }
  __syncthreads();
#pragma unroll
  for (int i = 0; i < 16; ++i) {
    int idx = t + 256 * i;
    int c = idx & 127, s = idx >> 7;
    ZB[(size_t)(row0 + s) * 128 + c] = (xs[s][c] - mu[s]) * rsd[s] * gs[c] + bs[c];
  }
}

// ---------------------------------------------------------------------------
// Kernel D: fc1 + exact GELU. ZB (B*Q,128) @ W1 (128,256). grid.y = j-half.
// ---------------------------------------------------------------------------
__global__ __launch_bounds__(256) void k_fc1_gelu(
    const float* __restrict__ ZB, const float* __restrict__ W1,
    const float* __restrict__ b1, float* __restrict__ HB)
{
  __shared__ float xs[32][132];
  __shared__ float wsm[64][128];
  const int t = threadIdx.x;
  const int row0 = blockIdx.x << 5;
  const int jh = blockIdx.y << 7;   // 0 or 128

#pragma unroll
  for (int i = 0; i < 16; ++i) {
    int idx = t + 256 * i;
    int c = idx & 127, s = idx >> 7;
    xs[s][c] = ZB[(size_t)(row0 + s) * 128 + c];
  }
  const int r0 = (t >> 5) << 2, j0 = (t & 31) << 2;
  float acc[4][4] = {};
  for (int cb = 0; cb < 2; ++cb) {
#pragma unroll
    for (int i = 0; i < 32; ++i) {
      int idx = t + 256 * i;
      int c = idx >> 7, j = idx & 127;
      wsm[c][j] = W1[(size_t)(cb * 64 + c) * 256 + jh + j];
    }
    __syncthreads();
    for (int c = 0; c < 64; c += 4) {
      float4 w0 = *(const float4*)&wsm[c][j0];
      float4 w1 = *(const float4*)&wsm[c + 1][j0];
      float4 w2 = *(const float4*)&wsm[c + 2][j0];
      float4 w3 = *(const float4*)&wsm[c + 3][j0];
#pragma unroll
      for (int i = 0; i < 4; ++i) {
        float4 xv = *(const float4*)&xs[r0 + i][cb * 64 + c];
        acc[i][0] += xv.x*w0.x + xv.y*w1.x + xv.z*w2.x + xv.w*w3.x;
        acc[i][1] += xv.x*w0.y + xv.y*w1.y + xv.z*w2.y + xv.w*w3.y;
        acc[i][2] += xv.x*w0.z + xv.y*w1.z + xv.z*w2.z + xv.w*w3.z;
        acc[i][3] += xv.x*w0.w + xv.y*w1.w + xv.z*w2.w + xv.w*w3.w;
      }
    }
    __syncthreads();
  }
  float4 bv = *(const float4*)&b1[jh + j0];
#pragma unroll
  for (int i = 0; i < 4; ++i) {
    float hx; float4 r;
    hx = acc[i][0] + bv.x; r.x = 0.5f * hx * (1.f + erff(hx * 0.7071067811865476f));
    hx = acc[i][1] + bv.y; r.y = 0.5f * hx * (1.f + erff(hx * 0.7071067811865476f));
    hx = acc[i][2] + bv.z; r.z = 0.5f * hx * (1.f + erff(hx * 0.7071067811865476f));
    hx = acc[i][3] + bv.w; r.w = 0.5f * hx * (1.f + erff(hx * 0.7071067811865476f));
    *(float4*)&HB[(size_t)(row0 + r0 + i) * 256 + jh + j0] = r;
  }
}

// ---------------------------------------------------------------------------
// Kernel E: fc2 + residual + post-LN + transposed store to (B, d, H, W).
// HB (B*Q,256) @ W2 (256,128)
// ---------------------------------------------------------------------------
__global__ __launch_bounds__(256) void k_fc2_res_ln_out(
    const float* __restrict__ HB, const float* __restrict__ W2,
    const float* __restrict__ b2, const float* __restrict__ ZB,
    const float* __restrict__ g, const float* __restrict__ bln,
    float* __restrict__ out)
{
  __shared__ float xs[32][260];     // input rows (256 wide); reused for y (cols 0..127)
  __shared__ float wsm[64][128];
  __shared__ float gs[128], bs[128];
  __shared__ float mu[32], rsd[32];
  const int t = threadIdx.x;
  const int row0 = blockIdx.x << 5;
  const int bb = row0 / Q_, hw0 = row0 % Q_;

  if (t < 128) { gs[t] = g[t]; bs[t] = bln[t]; }
#pragma unroll
  for (int i = 0; i < 32; ++i) {
    int idx = t + 256 * i;          // 8192
    int c = idx & 255, s = idx >> 8;
    xs[s][c] = HB[(size_t)(row0 + s) * 256 + c];
  }
  const int r0 = (t >> 5) << 2, j0 = (t & 31) << 2;
  float acc[4][4] = {};
  for (int cb = 0; cb < 4; ++cb) {
#pragma unroll
    for (int i = 0; i < 32; ++i) {
      int idx = t + 256 * i;
      int c = idx >> 7, j = idx & 127;
      wsm[c][j] = W2[(size_t)(cb * 64 + c) * 128 + j];
    }
    __syncthreads();
    for (int c = 0; c < 64; c += 4) {
      float4 w0 = *(const float4*)&wsm[c][j0];
      float4 w1 = *(const float4*)&wsm[c + 1][j0];
      float4 w2 = *(const float4*)&wsm[c + 2][j0];
      float4 w3 = *(const float4*)&wsm[c + 3][j0];
#pragma unroll
      for (int i = 0; i < 4; ++i) {
        float4 xv = *(const float4*)&xs[r0 + i][cb * 64 + c];
        acc[i][0] += xv.x*w0.x + xv.y*w1.x + xv.z*w2.x + xv.w*w3.x;
        acc[i][1] += xv.x*w0.y + xv.y*w1.y + xv.z*w2.y + xv.w*w3.y;
        acc[i][2] += xv.x*w0.z + xv.y*w1.z + xv.z*w2.z + xv.w*w3.z;
        acc[i][3] += xv.x*w0.w + xv.y*w1.w + xv.z*w2.w + xv.w*w3.w;
      }
    }
    __syncthreads();
  }
  float4 bv = *(const float4*)&b2[j0];
#pragma unroll
  for (int i = 0; i < 4; ++i) {
    float4 z = *(const float4*)&ZB[(size_t)(row0 + r0 + i) * 128 + j0];
    *(float4*)&xs[r0 + i][j0] = make_float4(acc[i][0] + bv.x + z.x,
                                            acc[i][1] + bv.y + z.y,
                                            acc[i][2] + bv.z + z.z,
                                            acc[i][3] + bv.w + z.w);
  }
  __syncthreads();
  {
    int s = t >> 3, l8 = t & 7;
    float sum = 0.f, sq = 0.f;
    for (int c = l8; c < 128; c += 8) { float v = xs[s][c]; sum += v; sq += v * v; }
#pragma unroll
    for (int off = 4; off > 0; off >>= 1) {
      sum += __shfl_down(sum, off, 8);
      sq  += __shfl_down(sq,  off, 8);
    }
    if (l8 == 0) {
      float m = sum * 0.0078125f;
      float var = sq * 0.0078125f - m * m;
      mu[s] = m; rsd[s] = rsqrtf(var + 1e-5f);
    }
  }
  __syncthreads();
#pragma unroll
  for (int i = 0; i < 16; ++i) {
    int idx = t + 256 * i;
    int s = idx & 31, c = idx >> 5;  // lanes -> consecutive hw (coalesced)
    out[(size_t)bb * (128 * (size_t)Q_) + (size_t)c * Q_ + hw0 + s] =
        (xs[s][c] - mu[s]) * rsd[s] * gs[c] + bs[c];
  }
}

// ---------------------------------------------------------------------------
extern "C" void kernel_launch(void* const* d_in, const int* in_sizes, int n_in,
                              void* d_out, int out_size, void* d_ws, size_t ws_size,
                              hipStream_t stream) {
  const float* q     = (const float*)d_in[0];
  const float* k     = (const float*)d_in[1];
  const float* v     = (const float*)d_in[2];
  const float* skip  = (const float*)d_in[3];
  const float* lnq_g = (const float*)d_in[4];
  const float* lnq_b = (const float*)d_in[5];
  const float* Wq    = (const float*)d_in[6];
  const float* bq    = (const float*)d_in[7];
  const float* lnk_g = (const float*)d_in[8];
  const float* lnk_b = (const float*)d_in[9];
  const float* Wk    = (const float*)d_in[10];
  const float* bk    = (const float*)d_in[11];
  const float* lnv_g = (const float*)d_in[12];
  const float* lnv_b = (const float*)d_in[13];
  const float* Wv    = (const float*)d_in[14];
  const float* bvv   = (const float*)d_in[15];
  const float* Wp    = (const float*)d_in[16];
  const float* bp    = (const float*)d_in[17];
  const float* pre_g = (const float*)d_in[18];
  const float* pre_b = (const float*)d_in[19];
  const float* W1    = (const float*)d_in[20];
  const float* b1    = (const float*)d_in[21];
  const float* W2    = (const float*)d_in[22];
  const float* b2    = (const float*)d_in[23];
  const float* post_g= (const float*)d_in[24];
  const float* post_b= (const float*)d_in[25];
  float* out = (float*)d_out;

  // Workspace layout (floats). Post-attention buffers alias dead QP region.
  float* ws = (float*)d_ws;
  float* QP = ws;                        // 3,538,944
  float* KP = QP + 3538944;              //   884,736
  float* VP = KP + 884736;               //   884,736
  float* AO = VP + 884736;               //   589,824  (peak: 23.6 MB)
  float* ZB = ws;                        //   589,824  (aliases QP after attn)
  float* HB = ws + 589824;               // 1,179,648  (aliases QP after attn)

  k_ln_proj<<<dim3(864), dim3(256), 0, stream>>>(q, lnq_g, lnq_b, Wq, bq, QP, Q_);
  k_ln_proj<<<dim3(216), dim3(256), 0, stream>>>(k, lnk_g, lnk_b, Wk, bk, KP, K_);
  k_ln_proj<<<dim3(216), dim3(256), 0, stream>>>(v, lnv_g, lnv_b, Wv, bvv, VP, K_);
  k_attn<<<dim3(1152), dim3(256), 0, stream>>>(QP, KP, VP, AO);
  k_proj_skip_ln<<<dim3(144), dim3(256), 0, stream>>>(AO, Wp, bp, skip, pre_g, pre_b, ZB);
  k_fc1_gelu<<<dim3(144, 2), dim3(256), 0, stream>>>(ZB, W1, b1, HB);
  k_fc2_res_ln_out<<<dim3(144), dim3(256), 0, stream>>>(HB, W2, b2, ZB, post_g, post_b, out);
}

// Round 2
// 287.110 us; speedup vs baseline: 2.2857x; 2.2857x over previous
//
#include <hip/hip_runtime.h>
#include <cmath>

// Shapes (fixed for this problem)
#define B_    2
#define N_    6
#define D_    128
#define Q_    2304      // 48*48
#define K_    576       // 24*24
#define NK_   3456      // N_*K_
#define HEADS_ 4
#define DH_   32
#define SCALE_ 0.17677669529663687f  // 1/sqrt(32)

typedef __attribute__((ext_vector_type(8))) short bf16x8;
typedef __attribute__((ext_vector_type(4))) float f32x4;

static __device__ __forceinline__ unsigned short f2bf(float f) {
  union { float f; unsigned u; } x; x.f = f;
  unsigned u = x.u + 0x7fffu + ((x.u >> 16) & 1u);   // RNE
  return (unsigned short)(u >> 16);
}

// ---------------------------------------------------------------------------
// Kernel A1: LayerNorm + projection, bf16 output (for Q and K).
// x: (O, 128, S) channel-major; out: (O, S, 128) bf16. oscale folds 1/sqrt(dh).
// ---------------------------------------------------------------------------
__global__ __launch_bounds__(256) void k_ln_proj_qk(
    const float* __restrict__ x, const float* __restrict__ g,
    const float* __restrict__ bln, const float* __restrict__ Wm,
    const float* __restrict__ bias, unsigned short* __restrict__ outh,
    int S, float oscale)
{
  __shared__ float xs[32][132];
  __shared__ float wsm[64][128];
  __shared__ float gs[128], bs[128];
  __shared__ float mu[32], rsd[32];
  const int t = threadIdx.x;
  const int ntile = S >> 5;
  const int o  = blockIdx.x / ntile;
  const int s0 = (blockIdx.x % ntile) << 5;

  if (t < 128) { gs[t] = g[t]; bs[t] = bln[t]; }
  const float* xb = x + (size_t)o * 128 * (size_t)S + s0;
#pragma unroll
  for (int i = 0; i < 16; ++i) {
    int idx = t + 256 * i;
    int c = idx >> 5, s = idx & 31;
    xs[s][c] = xb[(size_t)c * S + s];
  }
  __syncthreads();
  {
    int s = t >> 3, l8 = t & 7;
    float sum = 0.f, sq = 0.f;
    for (int c = l8; c < 128; c += 8) { float v = xs[s][c]; sum += v; sq += v * v; }
#pragma unroll
    for (int off = 4; off > 0; off >>= 1) {
      sum += __shfl_down(sum, off, 8);
      sq  += __shfl_down(sq,  off, 8);
    }
    if (l8 == 0) {
      float mth = sum * 0.0078125f;
      float var = sq * 0.0078125f - mth * mth;
      mu[s] = mth; rsd[s] = rsqrtf(var + 1e-5f);
    }
  }
  __syncthreads();
#pragma unroll
  for (int i = 0; i < 16; ++i) {
    int idx = t + 256 * i;
    int c = idx & 127, s = idx >> 7;
    xs[s][c] = (xs[s][c] - mu[s]) * rsd[s] * gs[c] + bs[c];
  }
  const int r0 = (t >> 5) << 2, j0 = (t & 31) << 2;
  float acc[4][4] = {};
  for (int cb = 0; cb < 2; ++cb) {
#pragma unroll
    for (int i = 0; i < 32; ++i) {
      int idx = t + 256 * i;
      int c = idx >> 7, j = idx & 127;
      wsm[c][j] = Wm[(size_t)(cb * 64 + c) * 128 + j];
    }
    __syncthreads();
    for (int c = 0; c < 64; c += 4) {
      float4 w0 = *(const float4*)&wsm[c][j0];
      float4 w1 = *(const float4*)&wsm[c + 1][j0];
      float4 w2 = *(const float4*)&wsm[c + 2][j0];
      float4 w3 = *(const float4*)&wsm[c + 3][j0];
#pragma unroll
      for (int i = 0; i < 4; ++i) {
        float4 xv = *(const float4*)&xs[r0 + i][cb * 64 + c];
        acc[i][0] += xv.x*w0.x + xv.y*w1.x + xv.z*w2.x + xv.w*w3.x;
        acc[i][1] += xv.x*w0.y + xv.y*w1.y + xv.z*w2.y + xv.w*w3.y;
        acc[i][2] += xv.x*w0.z + xv.y*w1.z + xv.z*w2.z + xv.w*w3.z;
        acc[i][3] += xv.x*w0.w + xv.y*w1.w + xv.z*w2.w + xv.w*w3.w;
      }
    }
    __syncthreads();
  }
  float4 bv = *(const float4*)&bias[j0];
#pragma unroll
  for (int i = 0; i < 4; ++i) {
    ushort4 r4;
    r4.x = f2bf((acc[i][0] + bv.x) * oscale);
    r4.y = f2bf((acc[i][1] + bv.y) * oscale);
    r4.z = f2bf((acc[i][2] + bv.z) * oscale);
    r4.w = f2bf((acc[i][3] + bv.w) * oscale);
    *(ushort4*)&outh[((size_t)o * S + s0 + r0 + i) * 128 + j0] = r4;
  }
}

// ---------------------------------------------------------------------------
// Kernel A2: LayerNorm + projection for V, stored TRANSPOSED bf16:
// VPT[b][h][dh(32)][NK(3456)]. Input x: (B*N, 128, 576).
// ---------------------------------------------------------------------------
__global__ __launch_bounds__(256) void k_ln_proj_vT(
    const float* __restrict__ x, const float* __restrict__ g,
    const float* __restrict__ bln, const float* __restrict__ Wm,
    const float* __restrict__ bias, unsigned short* __restrict__ VPTh)
{
  __shared__ float xs[32][132];
  __shared__ float wsm[64][128];
  __shared__ float gs[128], bs[128];
  __shared__ float mu[32], rsd[32];
  const int t = threadIdx.x;
  const int o  = blockIdx.x / 18;          // S=576 -> 18 tiles
  const int s0 = (blockIdx.x % 18) << 5;
  const int b = o / 6, n = o % 6;

  if (t < 128) { gs[t] = g[t]; bs[t] = bln[t]; }
  const float* xb = x + (size_t)o * 128 * 576 + s0;
#pragma unroll
  for (int i = 0; i < 16; ++i) {
    int idx = t + 256 * i;
    int c = idx >> 5, s = idx & 31;
    xs[s][c] = xb[(size_t)c * 576 + s];
  }
  __syncthreads();
  {
    int s = t >> 3, l8 = t & 7;
    float sum = 0.f, sq = 0.f;
    for (int c = l8; c < 128; c += 8) { float v = xs[s][c]; sum += v; sq += v * v; }
#pragma unroll
    for (int off = 4; off > 0; off >>= 1) {
      sum += __shfl_down(sum, off, 8);
      sq  += __shfl_down(sq,  off, 8);
    }
    if (l8 == 0) {
      float mth = sum * 0.0078125f;
      float var = sq * 0.0078125f - mth * mth;
      mu[s] = mth; rsd[s] = rsqrtf(var + 1e-5f);
    }
  }
  __syncthreads();
#pragma unroll
  for (int i = 0; i < 16; ++i) {
    int idx = t + 256 * i;
    int c = idx & 127, s = idx >> 7;
    xs[s][c] = (xs[s][c] - mu[s]) * rsd[s] * gs[c] + bs[c];
  }
  const int r0 = (t >> 5) << 2, j0 = (t & 31) << 2;
  float acc[4][4] = {};
  for (int cb = 0; cb < 2; ++cb) {
#pragma unroll
    for (int i = 0; i < 32; ++i) {
      int idx = t + 256 * i;
      int c = idx >> 7, j = idx & 127;
      wsm[c][j] = Wm[(size_t)(cb * 64 + c) * 128 + j];
    }
    __syncthreads();
    for (int c = 0; c < 64; c += 4) {
      float4 w0 = *(const float4*)&wsm[c][j0];
      float4 w1 = *(const float4*)&wsm[c + 1][j0];
      float4 w2 = *(const float4*)&wsm[c + 2][j0];
      float4 w3 = *(const float4*)&wsm[c + 3][j0];
#pragma unroll
      for (int i = 0; i < 4; ++i) {
        float4 xv = *(const float4*)&xs[r0 + i][cb * 64 + c];
        acc[i][0] += xv.x*w0.x + xv.y*w1.x + xv.z*w2.x + xv.w*w3.x;
        acc[i][1] += xv.x*w0.y + xv.y*w1.y + xv.z*w2.y + xv.w*w3.y;
        acc[i][2] += xv.x*w0.z + xv.y*w1.z + xv.z*w2.z + xv.w*w3.z;
        acc[i][3] += xv.x*w0.w + xv.y*w1.w + xv.z*w2.w + xv.w*w3.w;
      }
    }
    __syncthreads();
  }
  float4 bv = *(const float4*)&bias[j0];
#pragma unroll
  for (int i = 0; i < 4; ++i) {
    float vals[4] = {acc[i][0] + bv.x, acc[i][1] + bv.y,
                     acc[i][2] + bv.z, acc[i][3] + bv.w};
    int s = n * 576 + s0 + r0 + i;   // key index within batch b
#pragma unroll
    for (int jj = 0; jj < 4; ++jj) {
      int j = j0 + jj; int hh = j >> 5, dh = j & 31;
      VPTh[((size_t)(b * 4 + hh) * 32 + dh) * (size_t)NK_ + s] = f2bf(vals[jj]);
    }
  }
}

// ---------------------------------------------------------------------------
// Kernel B: MFMA flash attention. Block = 4 waves, 16 queries, split-K:
// wave w handles 32-key chunks kc = w, w+4, ... (108 chunks total, 27/wave).
// S^T orientation (A=K, B=Q) so softmax reduces over regs + 2 shuffles.
// P^T -> LDS bf16 -> A-layout b128 read. V from transposed global (B-layout).
// ---------------------------------------------------------------------------
__global__ __launch_bounds__(256) void k_attn_mfma(
    const unsigned short* __restrict__ QPh, const unsigned short* __restrict__ KPh,
    const unsigned short* __restrict__ VPTh, float* __restrict__ AO)
{
  __shared__ unsigned short pl[4][16][40];  // per-wave P tile, stride 40 halfs (80B)
  __shared__ float ol[4][16][32];           // O merge
  __shared__ float ml[4][16], ll[4][16];
  const int t = threadIdx.x;
  const int w = t >> 6, lane = t & 63;
  const int quad = lane >> 4, l16 = lane & 15;
  const int qt = blockIdx.x % 144, bh = blockIdx.x / 144;
  const int bb = bh >> 2, h = bh & 3;
  const int q0 = qt << 4;

  const unsigned short* vbase = VPTh + (size_t)(bb * 4 + h) * 32 * (size_t)NK_;
  const f32x4 zf = {0.f, 0.f, 0.f, 0.f};
  f32x4 o0 = zf, o1 = zf;
  float m = -INFINITY, lsum = 0.f;

  // fragment loader for chunk kcx (32 keys)
  auto loadF = [&](int kcx, bf16x8& a0, bf16x8& a1, bf16x8& qq, bf16x8& v0, bf16x8& v1) {
    int nn  = kcx / 18;                  // 18 chunks per view (576/32)
    int klx = (kcx - nn * 18) << 5;
    int k0x = kcx << 5;
    const unsigned short* kb = &KPh[((size_t)(bb * 6 + nn) * K_ + klx) * 128 + h * 32];
    a0 = *(const bf16x8*)&kb[(size_t)l16 * 128 + quad * 8];
    a1 = *(const bf16x8*)&kb[(size_t)(16 + l16) * 128 + quad * 8];
    qq = *(const bf16x8*)&QPh[((size_t)(bb * 6 + nn) * Q_ + q0 + l16) * 128 + h * 32 + quad * 8];
    v0 = *(const bf16x8*)&vbase[(size_t)l16 * NK_ + k0x + quad * 8];
    v1 = *(const bf16x8*)&vbase[(size_t)(16 + l16) * NK_ + k0x + quad * 8];
  };

  bf16x8 kf0, kf1, qc, vf0, vf1;
  loadF(w, kf0, kf1, qc, vf0, vf1);

  for (int kc = w; kc < 108; kc += 4) {
    // prefetch next chunk (redundant reload of current on last iter — harmless)
    bf16x8 nk0, nk1, nq, nv0, nv1;
    int kn = (kc + 4 < 108) ? kc + 4 : kc;
    loadF(kn, nk0, nk1, nq, nv0, nv1);

    // QK^T: S^T tiles D[key][q]; rows=key(quad*4+reg), col=q(l16)
    f32x4 s0 = __builtin_amdgcn_mfma_f32_16x16x32_bf16(kf0, qc, zf, 0, 0, 0);
    f32x4 s1 = __builtin_amdgcn_mfma_f32_16x16x32_bf16(kf1, qc, zf, 0, 0, 0);

    // online softmax for q = l16 (SCALE pre-folded into Q)
    float rmax = fmaxf(fmaxf(fmaxf(s0.x, s0.y), fmaxf(s0.z, s0.w)),
                       fmaxf(fmaxf(s1.x, s1.y), fmaxf(s1.z, s1.w)));
    rmax = fmaxf(rmax, __shfl_xor(rmax, 16));
    rmax = fmaxf(rmax, __shfl_xor(rmax, 32));
    float mn = fmaxf(m, rmax);
    float alpha = __expf(m - mn);
    m = mn;
    s0.x = __expf(s0.x - mn); s0.y = __expf(s0.y - mn);
    s0.z = __expf(s0.z - mn); s0.w = __expf(s0.w - mn);
    s1.x = __expf(s1.x - mn); s1.y = __expf(s1.y - mn);
    s1.z = __expf(s1.z - mn); s1.w = __expf(s1.w - mn);
    float rsum = (s0.x + s0.y + s0.z + s0.w) + (s1.x + s1.y + s1.z + s1.w);
    rsum += __shfl_xor(rsum, 16);
    rsum += __shfl_xor(rsum, 32);
    lsum = lsum * alpha + rsum;

    // O rescale: O rows are q=quad*4+r; fetch alpha for those q's
#pragma unroll
    for (int r = 0; r < 4; ++r) {
      float ar = __shfl(alpha, quad * 4 + r, 16);
      o0[r] *= ar; o1[r] *= ar;
    }

    // P^T (C-layout) -> LDS bf16 in [q][key] order for A-layout read
#pragma unroll
    for (int r = 0; r < 4; ++r) {
      pl[w][l16][quad * 4 + r]      = f2bf(s0[r]);
      pl[w][l16][16 + quad * 4 + r] = f2bf(s1[r]);
    }
    // A-frag: P[m=q=l16][k=key=quad*8+j] — 16B aligned (80B row stride)
    bf16x8 pf = *(const bf16x8*)&pl[w][l16][quad * 8];

    o0 = __builtin_amdgcn_mfma_f32_16x16x32_bf16(pf, vf0, o0, 0, 0, 0);
    o1 = __builtin_amdgcn_mfma_f32_16x16x32_bf16(pf, vf1, o1, 0, 0, 0);

    kf0 = nk0; kf1 = nk1; qc = nq; vf0 = nv0; vf1 = nv1;
  }

  // merge 4 waves' partial (m, l, O)
  if (lane < 16) { ml[w][lane] = m; ll[w][lane] = lsum; }
#pragma unroll
  for (int r = 0; r < 4; ++r) {
    ol[w][quad * 4 + r][l16]      = o0[r];
    ol[w][quad * 4 + r][16 + l16] = o1[r];
  }
  __syncthreads();
  {
    int q = t >> 4, dd = (t & 15) << 1;
    float mf = fmaxf(fmaxf(ml[0][q], ml[1][q]), fmaxf(ml[2][q], ml[3][q]));
    float den = 0.f, a0 = 0.f, a1 = 0.f;
#pragma unroll
    for (int ww = 0; ww < 4; ++ww) {
      float sc = __expf(ml[ww][q] - mf);
      den += ll[ww][q] * sc;
      a0  += ol[ww][q][dd] * sc;
      a1  += ol[ww][q][dd + 1] * sc;
    }
    float inv = 1.f / den;
    float2 r2; r2.x = a0 * inv; r2.y = a1 * inv;
    *(float2*)&AO[((size_t)bb * Q_ + q0 + q) * 128 + h * 32 + dd] = r2;
  }
}

// ---------------------------------------------------------------------------
// Kernel C: attention-out projection + bias + skip + pre-LN. (fp32, unchanged)
// ---------------------------------------------------------------------------
__global__ __launch_bounds__(256) void k_proj_skip_ln(
    const float* __restrict__ AO, const float* __restrict__ Wp,
    const float* __restrict__ bp, const float* __restrict__ skip,
    const float* __restrict__ g, const float* __restrict__ bln,
    float* __restrict__ ZB)
{
  __shared__ float xs[32][132];
  __shared__ float wsm[64][128];
  __shared__ float gs[128], bs[128];
  __shared__ float mu[32], rsd[32];
  const int t = threadIdx.x;
  const int row0 = blockIdx.x << 5;
  const int bb = row0 / Q_;
  const int hw0 = row0 % Q_;

  if (t < 128) { gs[t] = g[t]; bs[t] = bln[t]; }
#pragma unroll
  for (int i = 0; i < 16; ++i) {
    int idx = t + 256 * i;
    int c = idx & 127, s = idx >> 7;
    xs[s][c] = AO[(size_t)(row0 + s) * 128 + c];
  }
  const int r0 = (t >> 5) << 2, j0 = (t & 31) << 2;
  float acc[4][4] = {};
  for (int cb = 0; cb < 2; ++cb) {
#pragma unroll
    for (int i = 0; i < 32; ++i) {
      int idx = t + 256 * i;
      int c = idx >> 7, j = idx & 127;
      wsm[c][j] = Wp[(size_t)(cb * 64 + c) * 128 + j];
    }
    __syncthreads();
    for (int c = 0; c < 64; c += 4) {
      float4 w0 = *(const float4*)&wsm[c][j0];
      float4 w1 = *(const float4*)&wsm[c + 1][j0];
      float4 w2 = *(const float4*)&wsm[c + 2][j0];
      float4 w3 = *(const float4*)&wsm[c + 3][j0];
#pragma unroll
      for (int i = 0; i < 4; ++i) {
        float4 xv = *(const float4*)&xs[r0 + i][cb * 64 + c];
        acc[i][0] += xv.x*w0.x + xv.y*w1.x + xv.z*w2.x + xv.w*w3.x;
        acc[i][1] += xv.x*w0.y + xv.y*w1.y + xv.z*w2.y + xv.w*w3.y;
        acc[i][2] += xv.x*w0.z + xv.y*w1.z + xv.z*w2.z + xv.w*w3.z;
        acc[i][3] += xv.x*w0.w + xv.y*w1.w + xv.z*w2.w + xv.w*w3.w;
      }
    }
    __syncthreads();
  }
  float4 bv = *(const float4*)&bp[j0];
  float res[4][4];
#pragma unroll
  for (int i = 0; i < 4; ++i) {
    int hw = hw0 + r0 + i;
    res[i][0] = acc[i][0] + bv.x + skip[((size_t)bb * 128 + j0 + 0) * Q_ + hw];
    res[i][1] = acc[i][1] + bv.y + skip[((size_t)bb * 128 + j0 + 1) * Q_ + hw];
    res[i][2] = acc[i][2] + bv.z + skip[((size_t)bb * 128 + j0 + 2) * Q_ + hw];
    res[i][3] = acc[i][3] + bv.w + skip[((size_t)bb * 128 + j0 + 3) * Q_ + hw];
  }
#pragma unroll
  for (int i = 0; i < 4; ++i)
    *(float4*)&xs[r0 + i][j0] = make_float4(res[i][0], res[i][1], res[i][2], res[i][3]);
  __syncthreads();
  {
    int s = t >> 3, l8 = t & 7;
    float sum = 0.f, sq = 0.f;
    for (int c = l8; c < 128; c += 8) { float v = xs[s][c]; sum += v; sq += v * v; }
#pragma unroll
    for (int off = 4; off > 0; off >>= 1) {
      sum += __shfl_down(sum, off, 8);
      sq  += __shfl_down(sq,  off, 8);
    }
    if (l8 == 0) {
      float mth = sum * 0.0078125f;
      float var = sq * 0.0078125f - mth * mth;
      mu[s] = mth; rsd[s] = rsqrtf(var + 1e-5f);
    }
  }
  __syncthreads();
#pragma unroll
  for (int i = 0; i < 16; ++i) {
    int idx = t + 256 * i;
    int c = idx & 127, s = idx >> 7;
    ZB[(size_t)(row0 + s) * 128 + c] = (xs[s][c] - mu[s]) * rsd[s] * gs[c] + bs[c];
  }
}

// ---------------------------------------------------------------------------
// Kernel D: fc1 + exact GELU. (fp32, unchanged)
// ---------------------------------------------------------------------------
__global__ __launch_bounds__(256) void k_fc1_gelu(
    const float* __restrict__ ZB, const float* __restrict__ W1,
    const float* __restrict__ b1, float* __restrict__ HB)
{
  __shared__ float xs[32][132];
  __shared__ float wsm[64][128];
  const int t = threadIdx.x;
  const int row0 = blockIdx.x << 5;
  const int jh = blockIdx.y << 7;

#pragma unroll
  for (int i = 0; i < 16; ++i) {
    int idx = t + 256 * i;
    int c = idx & 127, s = idx >> 7;
    xs[s][c] = ZB[(size_t)(row0 + s) * 128 + c];
  }
  const int r0 = (t >> 5) << 2, j0 = (t & 31) << 2;
  float acc[4][4] = {};
  for (int cb = 0; cb < 2; ++cb) {
#pragma unroll
    for (int i = 0; i < 32; ++i) {
      int idx = t + 256 * i;
      int c = idx >> 7, j = idx & 127;
      wsm[c][j] = W1[(size_t)(cb * 64 + c) * 256 + jh + j];
    }
    __syncthreads();
    for (int c = 0; c < 64; c += 4) {
      float4 w0 = *(const float4*)&wsm[c][j0];
      float4 w1 = *(const float4*)&wsm[c + 1][j0];
      float4 w2 = *(const float4*)&wsm[c + 2][j0];
      float4 w3 = *(const float4*)&wsm[c + 3][j0];
#pragma unroll
      for (int i = 0; i < 4; ++i) {
        float4 xv = *(const float4*)&xs[r0 + i][cb * 64 + c];
        acc[i][0] += xv.x*w0.x + xv.y*w1.x + xv.z*w2.x + xv.w*w3.x;
        acc[i][1] += xv.x*w0.y + xv.y*w1.y + xv.z*w2.y + xv.w*w3.y;
        acc[i][2] += xv.x*w0.z + xv.y*w1.z + xv.z*w2.z + xv.w*w3.z;
        acc[i][3] += xv.x*w0.w + xv.y*w1.w + xv.z*w2.w + xv.w*w3.w;
      }
    }
    __syncthreads();
  }
  float4 bv = *(const float4*)&b1[jh + j0];
#pragma unroll
  for (int i = 0; i < 4; ++i) {
    float hx; float4 r;
    hx = acc[i][0] + bv.x; r.x = 0.5f * hx * (1.f + erff(hx * 0.7071067811865476f));
    hx = acc[i][1] + bv.y; r.y = 0.5f * hx * (1.f + erff(hx * 0.7071067811865476f));
    hx = acc[i][2] + bv.z; r.z = 0.5f * hx * (1.f + erff(hx * 0.7071067811865476f));
    hx = acc[i][3] + bv.w; r.w = 0.5f * hx * (1.f + erff(hx * 0.7071067811865476f));
    *(float4*)&HB[(size_t)(row0 + r0 + i) * 256 + jh + j0] = r;
  }
}

// ---------------------------------------------------------------------------
// Kernel E: fc2 + residual + post-LN + transposed store. (fp32, unchanged)
// ---------------------------------------------------------------------------
__global__ __launch_bounds__(256) void k_fc2_res_ln_out(
    const float* __restrict__ HB, const float* __restrict__ W2,
    const float* __restrict__ b2, const float* __restrict__ ZB,
    const float* __restrict__ g, const float* __restrict__ bln,
    float* __restrict__ out)
{
  __shared__ float xs[32][260];
  __shared__ float wsm[64][128];
  __shared__ float gs[128], bs[128];
  __shared__ float mu[32], rsd[32];
  const int t = threadIdx.x;
  const int row0 = blockIdx.x << 5;
  const int bb = row0 / Q_, hw0 = row0 % Q_;

  if (t < 128) { gs[t] = g[t]; bs[t] = bln[t]; }
#pragma unroll
  for (int i = 0; i < 32; ++i) {
    int idx = t + 256 * i;
    int c = idx & 255, s = idx >> 8;
    xs[s][c] = HB[(size_t)(row0 + s) * 256 + c];
  }
  const int r0 = (t >> 5) << 2, j0 = (t & 31) << 2;
  float acc[4][4] = {};
  for (int cb = 0; cb < 4; ++cb) {
#pragma unroll
    for (int i = 0; i < 32; ++i) {
      int idx = t + 256 * i;
      int c = idx >> 7, j = idx & 127;
      wsm[c][j] = W2[(size_t)(cb * 64 + c) * 128 + j];
    }
    __syncthreads();
    for (int c = 0; c < 64; c += 4) {
      float4 w0 = *(const float4*)&wsm[c][j0];
      float4 w1 = *(const float4*)&wsm[c + 1][j0];
      float4 w2 = *(const float4*)&wsm[c + 2][j0];
      float4 w3 = *(const float4*)&wsm[c + 3][j0];
#pragma unroll
      for (int i = 0; i < 4; ++i) {
        float4 xv = *(const float4*)&xs[r0 + i][cb * 64 + c];
        acc[i][0] += xv.x*w0.x + xv.y*w1.x + xv.z*w2.x + xv.w*w3.x;
        acc[i][1] += xv.x*w0.y + xv.y*w1.y + xv.z*w2.y + xv.w*w3.y;
        acc[i][2] += xv.x*w0.z + xv.y*w1.z + xv.z*w2.z + xv.w*w3.z;
        acc[i][3] += xv.x*w0.w + xv.y*w1.w + xv.z*w2.w + xv.w*w3.w;
      }
    }
    __syncthreads();
  }
  float4 bv = *(const float4*)&b2[j0];
#pragma unroll
  for (int i = 0; i < 4; ++i) {
    float4 z = *(const float4*)&ZB[(size_t)(row0 + r0 + i) * 128 + j0];
    *(float4*)&xs[r0 + i][j0] = make_float4(acc[i][0] + bv.x + z.x,
                                            acc[i][1] + bv.y + z.y,
                                            acc[i][2] + bv.z + z.z,
                                            acc[i][3] + bv.w + z.w);
  }
  __syncthreads();
  {
    int s = t >> 3, l8 = t & 7;
    float sum = 0.f, sq = 0.f;
    for (int c = l8; c < 128; c += 8) { float v = xs[s][c]; sum += v; sq += v * v; }
#pragma unroll
    for (int off = 4; off > 0; off >>= 1) {
      sum += __shfl_down(sum, off, 8);
      sq  += __shfl_down(sq,  off, 8);
    }
    if (l8 == 0) {
      float mth = sum * 0.0078125f;
      float var = sq * 0.0078125f - mth * mth;
      mu[s] = mth; rsd[s] = rsqrtf(var + 1e-5f);
    }
  }
  __syncthreads();
#pragma unroll
  for (int i = 0; i < 16; ++i) {
    int idx = t + 256 * i;
    int s = idx & 31, c = idx >> 5;
    out[(size_t)bb * (128 * (size_t)Q_) + (size_t)c * Q_ + hw0 + s] =
        (xs[s][c] - mu[s]) * rsd[s] * gs[c] + bs[c];
  }
}

// ---------------------------------------------------------------------------
extern "C" void kernel_launch(void* const* d_in, const int* in_sizes, int n_in,
                              void* d_out, int out_size, void* d_ws, size_t ws_size,
                              hipStream_t stream) {
  const float* q     = (const float*)d_in[0];
  const float* k     = (const float*)d_in[1];
  const float* v     = (const float*)d_in[2];
  const float* skip  = (const float*)d_in[3];
  const float* lnq_g = (const float*)d_in[4];
  const float* lnq_b = (const float*)d_in[5];
  const float* Wq    = (const float*)d_in[6];
  const float* bq    = (const float*)d_in[7];
  const float* lnk_g = (const float*)d_in[8];
  const float* lnk_b = (const float*)d_in[9];
  const float* Wk    = (const float*)d_in[10];
  const float* bk    = (const float*)d_in[11];
  const float* lnv_g = (const float*)d_in[12];
  const float* lnv_b = (const float*)d_in[13];
  const float* Wv    = (const float*)d_in[14];
  const float* bvv   = (const float*)d_in[15];
  const float* Wp    = (const float*)d_in[16];
  const float* bp    = (const float*)d_in[17];
  const float* pre_g = (const float*)d_in[18];
  const float* pre_b = (const float*)d_in[19];
  const float* W1    = (const float*)d_in[20];
  const float* b1    = (const float*)d_in[21];
  const float* W2    = (const float*)d_in[22];
  const float* b2    = (const float*)d_in[23];
  const float* post_g= (const float*)d_in[24];
  const float* post_b= (const float*)d_in[25];
  float* out = (float*)d_out;

  // Workspace layout. bf16 projections, fp32 AO; ZB/HB alias dead QP region.
  unsigned short* QPh  = (unsigned short*)d_ws;        // 3,538,944 halfs (7.08 MB)
  unsigned short* KPh  = QPh + 3538944;                //   884,736 halfs
  unsigned short* VPTh = KPh + 884736;                 //   884,736 halfs
  float* AO = (float*)(VPTh + 884736);                 //   589,824 floats
  float* ZB = (float*)d_ws;                            //   589,824 floats (alias QPh)
  float* HB = ZB + 589824;                             // 1,179,648 floats (alias QPh)

  k_ln_proj_qk<<<dim3(864), dim3(256), 0, stream>>>(q, lnq_g, lnq_b, Wq, bq, QPh, Q_, SCALE_);
  k_ln_proj_qk<<<dim3(216), dim3(256), 0, stream>>>(k, lnk_g, lnk_b, Wk, bk, KPh, K_, 1.0f);
  k_ln_proj_vT<<<dim3(216), dim3(256), 0, stream>>>(v, lnv_g, lnv_b, Wv, bvv, VPTh);
  k_attn_mfma<<<dim3(1152), dim3(256), 0, stream>>>(QPh, KPh, VPTh, AO);
  k_proj_skip_ln<<<dim3(144), dim3(256), 0, stream>>>(AO, Wp, bp, skip, pre_g, pre_b, ZB);
  k_fc1_gelu<<<dim3(144, 2), dim3(256), 0, stream>>>(ZB, W1, b1, HB);
  k_fc2_res_ln_out<<<dim3(144), dim3(256), 0, stream>>>(HB, W2, b2, ZB, post_g, post_b, out);
}

// Round 3
// 272.569 us; speedup vs baseline: 2.4077x; 1.0533x over previous
//
#include <hip/hip_runtime.h>
#include <cmath>

// Shapes (fixed for this problem)
#define B_    2
#define N_    6
#define D_    128
#define Q_    2304      // 48*48
#define K_    576       // 24*24
#define NK_   3456      // N_*K_
#define HEADS_ 4
#define DH_   32
#define SCALE_ 0.17677669529663687f  // 1/sqrt(32)

typedef __attribute__((ext_vector_type(8))) short bf16x8;
typedef __attribute__((ext_vector_type(4))) float f32x4;

static __device__ __forceinline__ unsigned short f2bf(float f) {
  union { float f; unsigned u; } x; x.f = f;
  unsigned u = x.u + 0x7fffu + ((x.u >> 16) & 1u);   // RNE
  return (unsigned short)(u >> 16);
}
static __device__ __forceinline__ unsigned pkbf(float a, float b) {
  return (unsigned)f2bf(a) | ((unsigned)f2bf(b) << 16);
}

// ---------------------------------------------------------------------------
// Kernel A1: LayerNorm + projection, bf16 output (for Q and K).
// x: (O, 128, S) channel-major; out: (O, S, 128) bf16. oscale folds 1/sqrt(dh).
// ---------------------------------------------------------------------------
__global__ __launch_bounds__(256) void k_ln_proj_qk(
    const float* __restrict__ x, const float* __restrict__ g,
    const float* __restrict__ bln, const float* __restrict__ Wm,
    const float* __restrict__ bias, unsigned short* __restrict__ outh,
    int S, float oscale)
{
  __shared__ float xs[32][132];
  __shared__ float wsm[64][128];
  __shared__ float gs[128], bs[128];
  __shared__ float mu[32], rsd[32];
  const int t = threadIdx.x;
  const int ntile = S >> 5;
  const int o  = blockIdx.x / ntile;
  const int s0 = (blockIdx.x % ntile) << 5;

  if (t < 128) { gs[t] = g[t]; bs[t] = bln[t]; }
  const float* xb = x + (size_t)o * 128 * (size_t)S + s0;
#pragma unroll
  for (int i = 0; i < 16; ++i) {
    int idx = t + 256 * i;
    int c = idx >> 5, s = idx & 31;
    xs[s][c] = xb[(size_t)c * S + s];
  }
  __syncthreads();
  {
    int s = t >> 3, l8 = t & 7;
    float sum = 0.f, sq = 0.f;
    for (int c = l8; c < 128; c += 8) { float v = xs[s][c]; sum += v; sq += v * v; }
#pragma unroll
    for (int off = 4; off > 0; off >>= 1) {
      sum += __shfl_down(sum, off, 8);
      sq  += __shfl_down(sq,  off, 8);
    }
    if (l8 == 0) {
      float mth = sum * 0.0078125f;
      float var = sq * 0.0078125f - mth * mth;
      mu[s] = mth; rsd[s] = rsqrtf(var + 1e-5f);
    }
  }
  __syncthreads();
#pragma unroll
  for (int i = 0; i < 16; ++i) {
    int idx = t + 256 * i;
    int c = idx & 127, s = idx >> 7;
    xs[s][c] = (xs[s][c] - mu[s]) * rsd[s] * gs[c] + bs[c];
  }
  const int r0 = (t >> 5) << 2, j0 = (t & 31) << 2;
  float acc[4][4] = {};
  for (int cb = 0; cb < 2; ++cb) {
#pragma unroll
    for (int i = 0; i < 32; ++i) {
      int idx = t + 256 * i;
      int c = idx >> 7, j = idx & 127;
      wsm[c][j] = Wm[(size_t)(cb * 64 + c) * 128 + j];
    }
    __syncthreads();
    for (int c = 0; c < 64; c += 4) {
      float4 w0 = *(const float4*)&wsm[c][j0];
      float4 w1 = *(const float4*)&wsm[c + 1][j0];
      float4 w2 = *(const float4*)&wsm[c + 2][j0];
      float4 w3 = *(const float4*)&wsm[c + 3][j0];
#pragma unroll
      for (int i = 0; i < 4; ++i) {
        float4 xv = *(const float4*)&xs[r0 + i][cb * 64 + c];
        acc[i][0] += xv.x*w0.x + xv.y*w1.x + xv.z*w2.x + xv.w*w3.x;
        acc[i][1] += xv.x*w0.y + xv.y*w1.y + xv.z*w2.y + xv.w*w3.y;
        acc[i][2] += xv.x*w0.z + xv.y*w1.z + xv.z*w2.z + xv.w*w3.z;
        acc[i][3] += xv.x*w0.w + xv.y*w1.w + xv.z*w2.w + xv.w*w3.w;
      }
    }
    __syncthreads();
  }
  float4 bv = *(const float4*)&bias[j0];
#pragma unroll
  for (int i = 0; i < 4; ++i) {
    ushort4 r4;
    r4.x = f2bf((acc[i][0] + bv.x) * oscale);
    r4.y = f2bf((acc[i][1] + bv.y) * oscale);
    r4.z = f2bf((acc[i][2] + bv.z) * oscale);
    r4.w = f2bf((acc[i][3] + bv.w) * oscale);
    *(ushort4*)&outh[((size_t)o * S + s0 + r0 + i) * 128 + j0] = r4;
  }
}

// ---------------------------------------------------------------------------
// Kernel A2: LayerNorm + projection for V, stored TRANSPOSED bf16:
// VPT[b][h][dh(32)][NK(3456)]. Input x: (B*N, 128, 576).
// ---------------------------------------------------------------------------
__global__ __launch_bounds__(256) void k_ln_proj_vT(
    const float* __restrict__ x, const float* __restrict__ g,
    const float* __restrict__ bln, const float* __restrict__ Wm,
    const float* __restrict__ bias, unsigned short* __restrict__ VPTh)
{
  __shared__ float xs[32][132];
  __shared__ float wsm[64][128];
  __shared__ float gs[128], bs[128];
  __shared__ float mu[32], rsd[32];
  const int t = threadIdx.x;
  const int o  = blockIdx.x / 18;          // S=576 -> 18 tiles
  const int s0 = (blockIdx.x % 18) << 5;
  const int b = o / 6, n = o % 6;

  if (t < 128) { gs[t] = g[t]; bs[t] = bln[t]; }
  const float* xb = x + (size_t)o * 128 * 576 + s0;
#pragma unroll
  for (int i = 0; i < 16; ++i) {
    int idx = t + 256 * i;
    int c = idx >> 5, s = idx & 31;
    xs[s][c] = xb[(size_t)c * 576 + s];
  }
  __syncthreads();
  {
    int s = t >> 3, l8 = t & 7;
    float sum = 0.f, sq = 0.f;
    for (int c = l8; c < 128; c += 8) { float v = xs[s][c]; sum += v; sq += v * v; }
#pragma unroll
    for (int off = 4; off > 0; off >>= 1) {
      sum += __shfl_down(sum, off, 8);
      sq  += __shfl_down(sq,  off, 8);
    }
    if (l8 == 0) {
      float mth = sum * 0.0078125f;
      float var = sq * 0.0078125f - mth * mth;
      mu[s] = mth; rsd[s] = rsqrtf(var + 1e-5f);
    }
  }
  __syncthreads();
#pragma unroll
  for (int i = 0; i < 16; ++i) {
    int idx = t + 256 * i;
    int c = idx & 127, s = idx >> 7;
    xs[s][c] = (xs[s][c] - mu[s]) * rsd[s] * gs[c] + bs[c];
  }
  const int r0 = (t >> 5) << 2, j0 = (t & 31) << 2;
  float acc[4][4] = {};
  for (int cb = 0; cb < 2; ++cb) {
#pragma unroll
    for (int i = 0; i < 32; ++i) {
      int idx = t + 256 * i;
      int c = idx >> 7, j = idx & 127;
      wsm[c][j] = Wm[(size_t)(cb * 64 + c) * 128 + j];
    }
    __syncthreads();
    for (int c = 0; c < 64; c += 4) {
      float4 w0 = *(const float4*)&wsm[c][j0];
      float4 w1 = *(const float4*)&wsm[c + 1][j0];
      float4 w2 = *(const float4*)&wsm[c + 2][j0];
      float4 w3 = *(const float4*)&wsm[c + 3][j0];
#pragma unroll
      for (int i = 0; i < 4; ++i) {
        float4 xv = *(const float4*)&xs[r0 + i][cb * 64 + c];
        acc[i][0] += xv.x*w0.x + xv.y*w1.x + xv.z*w2.x + xv.w*w3.x;
        acc[i][1] += xv.x*w0.y + xv.y*w1.y + xv.z*w2.y + xv.w*w3.y;
        acc[i][2] += xv.x*w0.z + xv.y*w1.z + xv.z*w2.z + xv.w*w3.z;
        acc[i][3] += xv.x*w0.w + xv.y*w1.w + xv.z*w2.w + xv.w*w3.w;
      }
    }
    __syncthreads();
  }
  float4 bv = *(const float4*)&bias[j0];
#pragma unroll
  for (int i = 0; i < 4; ++i) {
    float vals[4] = {acc[i][0] + bv.x, acc[i][1] + bv.y,
                     acc[i][2] + bv.z, acc[i][3] + bv.w};
    int s = n * 576 + s0 + r0 + i;   // key index within batch b
#pragma unroll
    for (int jj = 0; jj < 4; ++jj) {
      int j = j0 + jj; int hh = j >> 5, dh = j & 31;
      VPTh[((size_t)(b * 4 + hh) * 32 + dh) * (size_t)NK_ + s] = f2bf(vals[jj]);
    }
  }
}

// ---------------------------------------------------------------------------
// Kernel B: MFMA flash attention, NO-MAX softmax (scores provably small;
// clamp 70 for absolute safety; softmax is shift-invariant so result is exact).
// No cross-lane ops in the K-loop; PV MFMA accumulates O directly.
// Split-K 2-way across blocks; partial (O, l) written to global, merged later.
// Grid: 144 qtiles x 8 bh x 2 ksplit = 2304 blocks, 4 waves each.
// ---------------------------------------------------------------------------
__global__ __launch_bounds__(256) void k_attn_mfma(
    const unsigned short* __restrict__ QPh, const unsigned short* __restrict__ KPh,
    const unsigned short* __restrict__ VPTh, float* __restrict__ PO,
    float* __restrict__ Pl)
{
  __shared__ unsigned short plds[4][16][40];  // per-wave P tile (80B row stride)
  __shared__ float ol[4][16][32];             // O merge
  __shared__ float ll[4][4][16];              // per-(wave,quad) l partials
  const int t = threadIdx.x;
  const int w = t >> 6, lane = t & 63;
  const int quad = lane >> 4, l16 = lane & 15;
  const int qt = blockIdx.x % 144;
  const int rest = blockIdx.x / 144;          // 0..15
  const int bhx = rest >> 1, ks = rest & 1;
  const int bb = bhx >> 2, h = bhx & 3;
  const int q0 = qt << 4;

  const unsigned short* vbase = VPTh + (size_t)bhx * 32 * (size_t)NK_;
  const f32x4 zf = {0.f, 0.f, 0.f, 0.f};
  f32x4 o0 = zf, o1 = zf;
  float lsum = 0.f;

  const int m8 = ks * 4 + w;
  int c0 = (108 * m8) >> 3, c1 = (108 * (m8 + 1)) >> 3;   // 13-14 chunks/wave

  while (c0 < c1) {
    const int nn = c0 / 18;                                // current view
    const int cend = min(c1, (nn + 1) * 18);
    const unsigned short* kb = &KPh[((size_t)(bb * 6 + nn) * K_) * 128 + h * 32];
    bf16x8 qc = *(const bf16x8*)&QPh[((size_t)(bb * 6 + nn) * Q_ + q0 + l16) * 128 + h * 32 + quad * 8];

    // prefetch first chunk of segment
    int kl = (c0 - nn * 18) << 5;
    bf16x8 kf0 = *(const bf16x8*)&kb[(size_t)(kl + l16) * 128 + quad * 8];
    bf16x8 kf1 = *(const bf16x8*)&kb[(size_t)(kl + 16 + l16) * 128 + quad * 8];
    const unsigned short* vb = vbase + ((size_t)c0 << 5);
    bf16x8 vf0 = *(const bf16x8*)&vb[(size_t)l16 * NK_ + quad * 8];
    bf16x8 vf1 = *(const bf16x8*)&vb[(size_t)(16 + l16) * NK_ + quad * 8];

    for (int kc = c0; kc < cend; ++kc) {
      // prefetch next chunk (clamped; redundant reload on last iter)
      const int kn = (kc + 1 < cend) ? kc + 1 : kc;
      const int kln = (kn - nn * 18) << 5;
      bf16x8 nk0 = *(const bf16x8*)&kb[(size_t)(kln + l16) * 128 + quad * 8];
      bf16x8 nk1 = *(const bf16x8*)&kb[(size_t)(kln + 16 + l16) * 128 + quad * 8];
      const unsigned short* vbn = vbase + ((size_t)kn << 5);
      bf16x8 nv0 = *(const bf16x8*)&vbn[(size_t)l16 * NK_ + quad * 8];
      bf16x8 nv1 = *(const bf16x8*)&vbn[(size_t)(16 + l16) * NK_ + quad * 8];

      // S^T tiles D[key][q]: rows=key(quad*4+r), col=q(l16). SCALE folded in Q.
      f32x4 s0 = __builtin_amdgcn_mfma_f32_16x16x32_bf16(kf0, qc, zf, 0, 0, 0);
      f32x4 s1 = __builtin_amdgcn_mfma_f32_16x16x32_bf16(kf1, qc, zf, 0, 0, 0);

      float p00 = __expf(fminf(s0.x, 70.f)), p01 = __expf(fminf(s0.y, 70.f));
      float p02 = __expf(fminf(s0.z, 70.f)), p03 = __expf(fminf(s0.w, 70.f));
      float p10 = __expf(fminf(s1.x, 70.f)), p11 = __expf(fminf(s1.y, 70.f));
      float p12 = __expf(fminf(s1.z, 70.f)), p13 = __expf(fminf(s1.w, 70.f));
      lsum += (p00 + p01 + p02 + p03) + (p10 + p11 + p12 + p13);

      // P^T (C-layout) -> LDS bf16 [q][key], packed 32-bit writes
      *(unsigned*)&plds[w][l16][quad * 4]          = pkbf(p00, p01);
      *(unsigned*)&plds[w][l16][quad * 4 + 2]      = pkbf(p02, p03);
      *(unsigned*)&plds[w][l16][16 + quad * 4]     = pkbf(p10, p11);
      *(unsigned*)&plds[w][l16][16 + quad * 4 + 2] = pkbf(p12, p13);
      // A-frag read: P[m=q=l16][k=key=quad*8+j]
      bf16x8 pf = *(const bf16x8*)&plds[w][l16][quad * 8];

      o0 = __builtin_amdgcn_mfma_f32_16x16x32_bf16(pf, vf0, o0, 0, 0, 0);
      o1 = __builtin_amdgcn_mfma_f32_16x16x32_bf16(pf, vf1, o1, 0, 0, 0);

      kf0 = nk0; kf1 = nk1; vf0 = nv0; vf1 = nv1;
    }
    c0 = cend;
  }

  // intra-block merge: plain sums (no max)
  ll[w][quad][l16] = lsum;
#pragma unroll
  for (int r = 0; r < 4; ++r) {
    ol[w][quad * 4 + r][l16]      = o0[r];
    ol[w][quad * 4 + r][16 + l16] = o1[r];
  }
  __syncthreads();
  {
    const int q = t >> 4, i16 = t & 15, dd = i16 << 1;
    float a0 = 0.f, a1 = 0.f;
#pragma unroll
    for (int ww = 0; ww < 4; ++ww) { a0 += ol[ww][q][dd]; a1 += ol[ww][q][dd + 1]; }
    float2 r2; r2.x = a0; r2.y = a1;
    *(float2*)&PO[(((size_t)ks * 8 + bhx) * Q_ + q0 + q) * 32 + dd] = r2;
    if (i16 == 0) {
      float l = 0.f;
#pragma unroll
      for (int ww = 0; ww < 4; ++ww)
#pragma unroll
        for (int qq = 0; qq < 4; ++qq) l += ll[ww][qq][q];
      Pl[((size_t)ks * 8 + bhx) * Q_ + q0 + q] = l;
    }
  }
}

// ---------------------------------------------------------------------------
// Kernel B2: merge the 2 ksplit partials: AO = (O0+O1)/(l0+l1).
// 589824 outputs; grid 2304 x 256.
// ---------------------------------------------------------------------------
__global__ __launch_bounds__(256) void k_attn_merge(
    const float* __restrict__ PO, const float* __restrict__ Pl,
    float* __restrict__ AO)
{
  const int idx = blockIdx.x * 256 + threadIdx.x;     // 0..589823
  const int bhx = idx / 73728;                        // 73728 = 2304*32
  const int rem = idx - bhx * 73728;
  const int q = rem >> 5, dh = rem & 31;
  float o = PO[idx] + PO[589824 + idx];
  float l = Pl[bhx * Q_ + q] + Pl[8 * Q_ + bhx * Q_ + q];
  const int bbq = (bhx >> 2) * Q_ + q, h = bhx & 3;
  AO[(size_t)bbq * 128 + h * 32 + dh] = o / l;
}

// ---------------------------------------------------------------------------
// Kernel C: attention-out projection + bias + skip + pre-LN. (fp32, unchanged)
// ---------------------------------------------------------------------------
__global__ __launch_bounds__(256) void k_proj_skip_ln(
    const float* __restrict__ AO, const float* __restrict__ Wp,
    const float* __restrict__ bp, const float* __restrict__ skip,
    const float* __restrict__ g, const float* __restrict__ bln,
    float* __restrict__ ZB)
{
  __shared__ float xs[32][132];
  __shared__ float wsm[64][128];
  __shared__ float gs[128], bs[128];
  __shared__ float mu[32], rsd[32];
  const int t = threadIdx.x;
  const int row0 = blockIdx.x << 5;
  const int bb = row0 / Q_;
  const int hw0 = row0 % Q_;

  if (t < 128) { gs[t] = g[t]; bs[t] = bln[t]; }
#pragma unroll
  for (int i = 0; i < 16; ++i) {
    int idx = t + 256 * i;
    int c = idx & 127, s = idx >> 7;
    xs[s][c] = AO[(size_t)(row0 + s) * 128 + c];
  }
  const int r0 = (t >> 5) << 2, j0 = (t & 31) << 2;
  float acc[4][4] = {};
  for (int cb = 0; cb < 2; ++cb) {
#pragma unroll
    for (int i = 0; i < 32; ++i) {
      int idx = t + 256 * i;
      int c = idx >> 7, j = idx & 127;
      wsm[c][j] = Wp[(size_t)(cb * 64 + c) * 128 + j];
    }
    __syncthreads();
    for (int c = 0; c < 64; c += 4) {
      float4 w0 = *(const float4*)&wsm[c][j0];
      float4 w1 = *(const float4*)&wsm[c + 1][j0];
      float4 w2 = *(const float4*)&wsm[c + 2][j0];
      float4 w3 = *(const float4*)&wsm[c + 3][j0];
#pragma unroll
      for (int i = 0; i < 4; ++i) {
        float4 xv = *(const float4*)&xs[r0 + i][cb * 64 + c];
        acc[i][0] += xv.x*w0.x + xv.y*w1.x + xv.z*w2.x + xv.w*w3.x;
        acc[i][1] += xv.x*w0.y + xv.y*w1.y + xv.z*w2.y + xv.w*w3.y;
        acc[i][2] += xv.x*w0.z + xv.y*w1.z + xv.z*w2.z + xv.w*w3.z;
        acc[i][3] += xv.x*w0.w + xv.y*w1.w + xv.z*w2.w + xv.w*w3.w;
      }
    }
    __syncthreads();
  }
  float4 bv = *(const float4*)&bp[j0];
  float res[4][4];
#pragma unroll
  for (int i = 0; i < 4; ++i) {
    int hw = hw0 + r0 + i;
    res[i][0] = acc[i][0] + bv.x + skip[((size_t)bb * 128 + j0 + 0) * Q_ + hw];
    res[i][1] = acc[i][1] + bv.y + skip[((size_t)bb * 128 + j0 + 1) * Q_ + hw];
    res[i][2] = acc[i][2] + bv.z + skip[((size_t)bb * 128 + j0 + 2) * Q_ + hw];
    res[i][3] = acc[i][3] + bv.w + skip[((size_t)bb * 128 + j0 + 3) * Q_ + hw];
  }
#pragma unroll
  for (int i = 0; i < 4; ++i)
    *(float4*)&xs[r0 + i][j0] = make_float4(res[i][0], res[i][1], res[i][2], res[i][3]);
  __syncthreads();
  {
    int s = t >> 3, l8 = t & 7;
    float sum = 0.f, sq = 0.f;
    for (int c = l8; c < 128; c += 8) { float v = xs[s][c]; sum += v; sq += v * v; }
#pragma unroll
    for (int off = 4; off > 0; off >>= 1) {
      sum += __shfl_down(sum, off, 8);
      sq  += __shfl_down(sq,  off, 8);
    }
    if (l8 == 0) {
      float mth = sum * 0.0078125f;
      float var = sq * 0.0078125f - mth * mth;
      mu[s] = mth; rsd[s] = rsqrtf(var + 1e-5f);
    }
  }
  __syncthreads();
#pragma unroll
  for (int i = 0; i < 16; ++i) {
    int idx = t + 256 * i;
    int c = idx & 127, s = idx >> 7;
    ZB[(size_t)(row0 + s) * 128 + c] = (xs[s][c] - mu[s]) * rsd[s] * gs[c] + bs[c];
  }
}

// ---------------------------------------------------------------------------
// Kernel D: fc1 + exact GELU. (fp32, unchanged)
// ---------------------------------------------------------------------------
__global__ __launch_bounds__(256) void k_fc1_gelu(
    const float* __restrict__ ZB, const float* __restrict__ W1,
    const float* __restrict__ b1, float* __restrict__ HB)
{
  __shared__ float xs[32][132];
  __shared__ float wsm[64][128];
  const int t = threadIdx.x;
  const int row0 = blockIdx.x << 5;
  const int jh = blockIdx.y << 7;

#pragma unroll
  for (int i = 0; i < 16; ++i) {
    int idx = t + 256 * i;
    int c = idx & 127, s = idx >> 7;
    xs[s][c] = ZB[(size_t)(row0 + s) * 128 + c];
  }
  const int r0 = (t >> 5) << 2, j0 = (t & 31) << 2;
  float acc[4][4] = {};
  for (int cb = 0; cb < 2; ++cb) {
#pragma unroll
    for (int i = 0; i < 32; ++i) {
      int idx = t + 256 * i;
      int c = idx >> 7, j = idx & 127;
      wsm[c][j] = W1[(size_t)(cb * 64 + c) * 256 + jh + j];
    }
    __syncthreads();
    for (int c = 0; c < 64; c += 4) {
      float4 w0 = *(const float4*)&wsm[c][j0];
      float4 w1 = *(const float4*)&wsm[c + 1][j0];
      float4 w2 = *(const float4*)&wsm[c + 2][j0];
      float4 w3 = *(const float4*)&wsm[c + 3][j0];
#pragma unroll
      for (int i = 0; i < 4; ++i) {
        float4 xv = *(const float4*)&xs[r0 + i][cb * 64 + c];
        acc[i][0] += xv.x*w0.x + xv.y*w1.x + xv.z*w2.x + xv.w*w3.x;
        acc[i][1] += xv.x*w0.y + xv.y*w1.y + xv.z*w2.y + xv.w*w3.y;
        acc[i][2] += xv.x*w0.z + xv.y*w1.z + xv.z*w2.z + xv.w*w3.z;
        acc[i][3] += xv.x*w0.w + xv.y*w1.w + xv.z*w2.w + xv.w*w3.w;
      }
    }
    __syncthreads();
  }
  float4 bv = *(const float4*)&b1[jh + j0];
#pragma unroll
  for (int i = 0; i < 4; ++i) {
    float hx; float4 r;
    hx = acc[i][0] + bv.x; r.x = 0.5f * hx * (1.f + erff(hx * 0.7071067811865476f));
    hx = acc[i][1] + bv.y; r.y = 0.5f * hx * (1.f + erff(hx * 0.7071067811865476f));
    hx = acc[i][2] + bv.z; r.z = 0.5f * hx * (1.f + erff(hx * 0.7071067811865476f));
    hx = acc[i][3] + bv.w; r.w = 0.5f * hx * (1.f + erff(hx * 0.7071067811865476f));
    *(float4*)&HB[(size_t)(row0 + r0 + i) * 256 + jh + j0] = r;
  }
}

// ---------------------------------------------------------------------------
// Kernel E: fc2 + residual + post-LN + transposed store. (fp32, unchanged)
// ---------------------------------------------------------------------------
__global__ __launch_bounds__(256) void k_fc2_res_ln_out(
    const float* __restrict__ HB, const float* __restrict__ W2,
    const float* __restrict__ b2, const float* __restrict__ ZB,
    const float* __restrict__ g, const float* __restrict__ bln,
    float* __restrict__ out)
{
  __shared__ float xs[32][260];
  __shared__ float wsm[64][128];
  __shared__ float gs[128], bs[128];
  __shared__ float mu[32], rsd[32];
  const int t = threadIdx.x;
  const int row0 = blockIdx.x << 5;
  const int bb = row0 / Q_, hw0 = row0 % Q_;

  if (t < 128) { gs[t] = g[t]; bs[t] = bln[t]; }
#pragma unroll
  for (int i = 0; i < 32; ++i) {
    int idx = t + 256 * i;
    int c = idx & 255, s = idx >> 8;
    xs[s][c] = HB[(size_t)(row0 + s) * 256 + c];
  }
  const int r0 = (t >> 5) << 2, j0 = (t & 31) << 2;
  float acc[4][4] = {};
  for (int cb = 0; cb < 4; ++cb) {
#pragma unroll
    for (int i = 0; i < 32; ++i) {
      int idx = t + 256 * i;
      int c = idx >> 7, j = idx & 127;
      wsm[c][j] = W2[(size_t)(cb * 64 + c) * 128 + j];
    }
    __syncthreads();
    for (int c = 0; c < 64; c += 4) {
      float4 w0 = *(const float4*)&wsm[c][j0];
      float4 w1 = *(const float4*)&wsm[c + 1][j0];
      float4 w2 = *(const float4*)&wsm[c + 2][j0];
      float4 w3 = *(const float4*)&wsm[c + 3][j0];
#pragma unroll
      for (int i = 0; i < 4; ++i) {
        float4 xv = *(const float4*)&xs[r0 + i][cb * 64 + c];
        acc[i][0] += xv.x*w0.x + xv.y*w1.x + xv.z*w2.x + xv.w*w3.x;
        acc[i][1] += xv.x*w0.y + xv.y*w1.y + xv.z*w2.y + xv.w*w3.y;
        acc[i][2] += xv.x*w0.z + xv.y*w1.z + xv.z*w2.z + xv.w*w3.z;
        acc[i][3] += xv.x*w0.w + xv.y*w1.w + xv.z*w2.w + xv.w*w3.w;
      }
    }
    __syncthreads();
  }
  float4 bv = *(const float4*)&b2[j0];
#pragma unroll
  for (int i = 0; i < 4; ++i) {
    float4 z = *(const float4*)&ZB[(size_t)(row0 + r0 + i) * 128 + j0];
    *(float4*)&xs[r0 + i][j0] = make_float4(acc[i][0] + bv.x + z.x,
                                            acc[i][1] + bv.y + z.y,
                                            acc[i][2] + bv.z + z.z,
                                            acc[i][3] + bv.w + z.w);
  }
  __syncthreads();
  {
    int s = t >> 3, l8 = t & 7;
    float sum = 0.f, sq = 0.f;
    for (int c = l8; c < 128; c += 8) { float v = xs[s][c]; sum += v; sq += v * v; }
#pragma unroll
    for (int off = 4; off > 0; off >>= 1) {
      sum += __shfl_down(sum, off, 8);
      sq  += __shfl_down(sq,  off, 8);
    }
    if (l8 == 0) {
      float mth = sum * 0.0078125f;
      float var = sq * 0.0078125f - mth * mth;
      mu[s] = mth; rsd[s] = rsqrtf(var + 1e-5f);
    }
  }
  __syncthreads();
#pragma unroll
  for (int i = 0; i < 16; ++i) {
    int idx = t + 256 * i;
    int s = idx & 31, c = idx >> 5;
    out[(size_t)bb * (128 * (size_t)Q_) + (size_t)c * Q_ + hw0 + s] =
        (xs[s][c] - mu[s]) * rsd[s] * gs[c] + bs[c];
  }
}

// ---------------------------------------------------------------------------
extern "C" void kernel_launch(void* const* d_in, const int* in_sizes, int n_in,
                              void* d_out, int out_size, void* d_ws, size_t ws_size,
                              hipStream_t stream) {
  const float* q     = (const float*)d_in[0];
  const float* k     = (const float*)d_in[1];
  const float* v     = (const float*)d_in[2];
  const float* skip  = (const float*)d_in[3];
  const float* lnq_g = (const float*)d_in[4];
  const float* lnq_b = (const float*)d_in[5];
  const float* Wq    = (const float*)d_in[6];
  const float* bq    = (const float*)d_in[7];
  const float* lnk_g = (const float*)d_in[8];
  const float* lnk_b = (const float*)d_in[9];
  const float* Wk    = (const float*)d_in[10];
  const float* bk    = (const float*)d_in[11];
  const float* lnv_g = (const float*)d_in[12];
  const float* lnv_b = (const float*)d_in[13];
  const float* Wv    = (const float*)d_in[14];
  const float* bvv   = (const float*)d_in[15];
  const float* Wp    = (const float*)d_in[16];
  const float* bp    = (const float*)d_in[17];
  const float* pre_g = (const float*)d_in[18];
  const float* pre_b = (const float*)d_in[19];
  const float* W1    = (const float*)d_in[20];
  const float* b1    = (const float*)d_in[21];
  const float* W2    = (const float*)d_in[22];
  const float* b2    = (const float*)d_in[23];
  const float* post_g= (const float*)d_in[24];
  const float* post_b= (const float*)d_in[25];
  float* out = (float*)d_out;

  // Workspace layout. bf16 projections; fp32 partials; ZB/HB alias dead QPh.
  unsigned short* QPh  = (unsigned short*)d_ws;        // 3,538,944 halfs (7.08 MB)
  unsigned short* KPh  = QPh + 3538944;                //   884,736 halfs
  unsigned short* VPTh = KPh + 884736;                 //   884,736 halfs
  float* AO = (float*)(VPTh + 884736);                 //   589,824 floats
  float* PO = AO + 589824;                             // 1,179,648 floats
  float* Pl = PO + 1179648;                            //    36,864 floats
  float* ZB = (float*)d_ws;                            //   589,824 floats (alias QPh)
  float* HB = ZB + 589824;                             // 1,179,648 floats (alias QPh)

  k_ln_proj_qk<<<dim3(864), dim3(256), 0, stream>>>(q, lnq_g, lnq_b, Wq, bq, QPh, Q_, SCALE_);
  k_ln_proj_qk<<<dim3(216), dim3(256), 0, stream>>>(k, lnk_g, lnk_b, Wk, bk, KPh, K_, 1.0f);
  k_ln_proj_vT<<<dim3(216), dim3(256), 0, stream>>>(v, lnv_g, lnv_b, Wv, bvv, VPTh);
  k_attn_mfma<<<dim3(2304), dim3(256), 0, stream>>>(QPh, KPh, VPTh, PO, Pl);
  k_attn_merge<<<dim3(2304), dim3(256), 0, stream>>>(PO, Pl, AO);
  k_proj_skip_ln<<<dim3(144), dim3(256), 0, stream>>>(AO, Wp, bp, skip, pre_g, pre_b, ZB);
  k_fc1_gelu<<<dim3(144, 2), dim3(256), 0, stream>>>(ZB, W1, b1, HB);
  k_fc2_res_ln_out<<<dim3(144), dim3(256), 0, stream>>>(HB, W2, b2, ZB, post_g, post_b, out);
}

// Round 4
// 216.870 us; speedup vs baseline: 3.0261x; 1.2568x over previous
//
#include <hip/hip_runtime.h>
#include <cmath>

// Shapes (fixed for this problem)
#define B_    2
#define N_    6
#define D_    128
#define Q_    2304      // 48*48
#define K_    576       // 24*24
#define NK_   3456      // N_*K_
#define HEADS_ 4
#define DH_   32
#define SCALE_ 0.17677669529663687f  // 1/sqrt(32)

typedef __attribute__((ext_vector_type(8))) short bf16x8;
typedef __attribute__((ext_vector_type(4))) float f32x4;

static __device__ __forceinline__ unsigned short f2bf(float f) {
  union { float f; unsigned u; } x; x.f = f;
  unsigned u = x.u + 0x7fffu + ((x.u >> 16) & 1u);   // RNE
  return (unsigned short)(u >> 16);
}
static __device__ __forceinline__ unsigned pkbf(float a, float b) {
  return (unsigned)f2bf(a) | ((unsigned)f2bf(b) << 16);
}

// ---------------------------------------------------------------------------
// Kernel P: transpose+convert all weights to bf16 WT[n][k] (MFMA B-frag
// layout: lane(quad,l16) reads WT[col l16][quad*8..+7] as one 16B load).
// 128 blocks, one 32x32 tile each.
// ---------------------------------------------------------------------------
__global__ __launch_bounds__(256) void k_prep_wt(
    const float* __restrict__ Wq, const float* __restrict__ Wk,
    const float* __restrict__ Wv, const float* __restrict__ Wp,
    const float* __restrict__ W1, const float* __restrict__ W2,
    unsigned short* __restrict__ WTq, unsigned short* __restrict__ WTk,
    unsigned short* __restrict__ WTv, unsigned short* __restrict__ WTp,
    unsigned short* __restrict__ WT1, unsigned short* __restrict__ WT2)
{
  __shared__ float tile[32][33];
  const int wb = blockIdx.x, t = threadIdx.x;
  const float* src; unsigned short* dst; int Kd, J, tl;
  if      (wb < 16) { src = Wq; dst = WTq; Kd = 128; J = 128; tl = wb; }
  else if (wb < 32) { src = Wk; dst = WTk; Kd = 128; J = 128; tl = wb - 16; }
  else if (wb < 48) { src = Wv; dst = WTv; Kd = 128; J = 128; tl = wb - 32; }
  else if (wb < 64) { src = Wp; dst = WTp; Kd = 128; J = 128; tl = wb - 48; }
  else if (wb < 96) { src = W1; dst = WT1; Kd = 128; J = 256; tl = wb - 64; }
  else              { src = W2; dst = WT2; Kd = 256; J = 128; tl = wb - 96; }
  const int njt = J >> 5;
  const int tj = tl % njt, tk = tl / njt;
#pragma unroll
  for (int i = 0; i < 4; ++i) {
    int idx = t + 256 * i;
    int r = idx >> 5, c = idx & 31;
    tile[r][c] = src[(size_t)(tk * 32 + r) * J + tj * 32 + c];
  }
  __syncthreads();
#pragma unroll
  for (int i = 0; i < 2; ++i) {
    int idx = t + 256 * i;               // 512 pairs
    int rr = idx >> 4, c2 = (idx & 15) << 1;
    *(unsigned*)&dst[(size_t)(tj * 32 + rr) * Kd + tk * 32 + c2] =
        pkbf(tile[c2][rr], tile[c2 + 1][rr]);
  }
}

// ---------------------------------------------------------------------------
// Kernel A1: LN + MFMA projection, bf16 out (Q and K). x:(O,128,S) ch-major.
// ---------------------------------------------------------------------------
__global__ __launch_bounds__(256) void k_ln_proj_qk(
    const float* __restrict__ x, const float* __restrict__ g,
    const float* __restrict__ bln, const unsigned short* __restrict__ WT,
    const float* __restrict__ bias, unsigned short* __restrict__ outh,
    int S, float oscale)
{
  __shared__ float xs[32][132];
  __shared__ unsigned short xh[32][136];
  __shared__ float gs[128], bs[128];
  __shared__ float mu[32], rsd[32];
  const int t = threadIdx.x;
  const int ntile = S >> 5;
  const int o  = blockIdx.x / ntile;
  const int s0 = (blockIdx.x % ntile) << 5;

  if (t < 128) { gs[t] = g[t]; bs[t] = bln[t]; }
  const float* xb = x + (size_t)o * 128 * (size_t)S + s0;
#pragma unroll
  for (int i = 0; i < 16; ++i) {
    int idx = t + 256 * i;
    int c = idx >> 5, s = idx & 31;
    xs[s][c] = xb[(size_t)c * S + s];
  }
  __syncthreads();
  {
    int s = t >> 3, l8 = t & 7;
    float sum = 0.f, sq = 0.f;
    for (int c = l8; c < 128; c += 8) { float v = xs[s][c]; sum += v; sq += v * v; }
#pragma unroll
    for (int off = 4; off > 0; off >>= 1) {
      sum += __shfl_down(sum, off, 8);
      sq  += __shfl_down(sq,  off, 8);
    }
    if (l8 == 0) {
      float mth = sum * 0.0078125f;
      float var = sq * 0.0078125f - mth * mth;
      mu[s] = mth; rsd[s] = rsqrtf(var + 1e-5f);
    }
  }
  __syncthreads();
#pragma unroll
  for (int i = 0; i < 8; ++i) {
    int idx = t + 256 * i;               // 2048 pairs
    int s = idx >> 6, c2 = (idx & 63) << 1;
    float y0 = (xs[s][c2]     - mu[s]) * rsd[s] * gs[c2]     + bs[c2];
    float y1 = (xs[s][c2 + 1] - mu[s]) * rsd[s] * gs[c2 + 1] + bs[c2 + 1];
    *(unsigned*)&xh[s][c2] = pkbf(y0, y1);
  }
  __syncthreads();
  const int w = t >> 6, lane = t & 63, quad = lane >> 4, l16 = lane & 15;
  const f32x4 zf = {0.f, 0.f, 0.f, 0.f};
  f32x4 acc[2][2] = {{zf, zf}, {zf, zf}};
#pragma unroll
  for (int kc = 0; kc < 4; ++kc) {
    bf16x8 a0 = *(const bf16x8*)&xh[l16][kc * 32 + quad * 8];
    bf16x8 a1 = *(const bf16x8*)&xh[16 + l16][kc * 32 + quad * 8];
    bf16x8 b0 = *(const bf16x8*)&WT[(size_t)(w * 32 + l16) * 128 + kc * 32 + quad * 8];
    bf16x8 b1 = *(const bf16x8*)&WT[(size_t)(w * 32 + 16 + l16) * 128 + kc * 32 + quad * 8];
    acc[0][0] = __builtin_amdgcn_mfma_f32_16x16x32_bf16(a0, b0, acc[0][0], 0, 0, 0);
    acc[0][1] = __builtin_amdgcn_mfma_f32_16x16x32_bf16(a0, b1, acc[0][1], 0, 0, 0);
    acc[1][0] = __builtin_amdgcn_mfma_f32_16x16x32_bf16(a1, b0, acc[1][0], 0, 0, 0);
    acc[1][1] = __builtin_amdgcn_mfma_f32_16x16x32_bf16(a1, b1, acc[1][1], 0, 0, 0);
  }
  __syncthreads();                        // xh reused as output staging
#pragma unroll
  for (int mt = 0; mt < 2; ++mt)
#pragma unroll
    for (int nt = 0; nt < 2; ++nt) {
      int col = w * 32 + nt * 16 + l16;
      float bc = bias[col];
#pragma unroll
      for (int r = 0; r < 4; ++r)
        xh[mt * 16 + quad * 4 + r][col] = f2bf((acc[mt][nt][r] + bc) * oscale);
    }
  __syncthreads();
#pragma unroll
  for (int i = 0; i < 2; ++i) {
    int s = i * 16 + (t >> 4), c8 = (t & 15) << 3;
    *(uint4*)&outh[((size_t)o * S + s0 + s) * 128 + c8] = *(uint4*)&xh[s][c8];
  }
}

// ---------------------------------------------------------------------------
// Kernel A2: LN + MFMA projection for V, stored TRANSPOSED bf16:
// VPT[b][h][dh(32)][NK(3456)].
// ---------------------------------------------------------------------------
__global__ __launch_bounds__(256) void k_ln_proj_vT(
    const float* __restrict__ x, const float* __restrict__ g,
    const float* __restrict__ bln, const unsigned short* __restrict__ WT,
    const float* __restrict__ bias, unsigned short* __restrict__ VPTh)
{
  __shared__ float xs[32][132];
  __shared__ unsigned short xh[32][136];
  __shared__ float gs[128], bs[128];
  __shared__ float mu[32], rsd[32];
  const int t = threadIdx.x;
  const int o  = blockIdx.x / 18;
  const int s0 = (blockIdx.x % 18) << 5;
  const int b = o / 6, n = o % 6;

  if (t < 128) { gs[t] = g[t]; bs[t] = bln[t]; }
  const float* xb = x + (size_t)o * 128 * 576 + s0;
#pragma unroll
  for (int i = 0; i < 16; ++i) {
    int idx = t + 256 * i;
    int c = idx >> 5, s = idx & 31;
    xs[s][c] = xb[(size_t)c * 576 + s];
  }
  __syncthreads();
  {
    int s = t >> 3, l8 = t & 7;
    float sum = 0.f, sq = 0.f;
    for (int c = l8; c < 128; c += 8) { float v = xs[s][c]; sum += v; sq += v * v; }
#pragma unroll
    for (int off = 4; off > 0; off >>= 1) {
      sum += __shfl_down(sum, off, 8);
      sq  += __shfl_down(sq,  off, 8);
    }
    if (l8 == 0) {
      float mth = sum * 0.0078125f;
      float var = sq * 0.0078125f - mth * mth;
      mu[s] = mth; rsd[s] = rsqrtf(var + 1e-5f);
    }
  }
  __syncthreads();
#pragma unroll
  for (int i = 0; i < 8; ++i) {
    int idx = t + 256 * i;
    int s = idx >> 6, c2 = (idx & 63) << 1;
    float y0 = (xs[s][c2]     - mu[s]) * rsd[s] * gs[c2]     + bs[c2];
    float y1 = (xs[s][c2 + 1] - mu[s]) * rsd[s] * gs[c2 + 1] + bs[c2 + 1];
    *(unsigned*)&xh[s][c2] = pkbf(y0, y1);
  }
  __syncthreads();
  const int w = t >> 6, lane = t & 63, quad = lane >> 4, l16 = lane & 15;
  const f32x4 zf = {0.f, 0.f, 0.f, 0.f};
  f32x4 acc[2][2] = {{zf, zf}, {zf, zf}};
#pragma unroll
  for (int kc = 0; kc < 4; ++kc) {
    bf16x8 a0 = *(const bf16x8*)&xh[l16][kc * 32 + quad * 8];
    bf16x8 a1 = *(const bf16x8*)&xh[16 + l16][kc * 32 + quad * 8];
    bf16x8 b0 = *(const bf16x8*)&WT[(size_t)(w * 32 + l16) * 128 + kc * 32 + quad * 8];
    bf16x8 b1 = *(const bf16x8*)&WT[(size_t)(w * 32 + 16 + l16) * 128 + kc * 32 + quad * 8];
    acc[0][0] = __builtin_amdgcn_mfma_f32_16x16x32_bf16(a0, b0, acc[0][0], 0, 0, 0);
    acc[0][1] = __builtin_amdgcn_mfma_f32_16x16x32_bf16(a0, b1, acc[0][1], 0, 0, 0);
    acc[1][0] = __builtin_amdgcn_mfma_f32_16x16x32_bf16(a1, b0, acc[1][0], 0, 0, 0);
    acc[1][1] = __builtin_amdgcn_mfma_f32_16x16x32_bf16(a1, b1, acc[1][1], 0, 0, 0);
  }
  // transposed store: 4 consecutive keys (rows) at fixed (h,dh) -> ushort4
#pragma unroll
  for (int mt = 0; mt < 2; ++mt)
#pragma unroll
    for (int nt = 0; nt < 2; ++nt) {
      int col = w * 32 + nt * 16 + l16;
      int hh = col >> 5, dh = col & 31;
      float bc = bias[col];
      ushort4 pk;
      pk.x = f2bf(acc[mt][nt][0] + bc); pk.y = f2bf(acc[mt][nt][1] + bc);
      pk.z = f2bf(acc[mt][nt][2] + bc); pk.w = f2bf(acc[mt][nt][3] + bc);
      int s = n * 576 + s0 + mt * 16 + quad * 4;
      *(ushort4*)&VPTh[((size_t)(b * 4 + hh) * 32 + dh) * (size_t)NK_ + s] = pk;
    }
}

// ---------------------------------------------------------------------------
// Kernel B: MFMA flash attention, no-max softmax, split-K 2-way. (unchanged)
// ---------------------------------------------------------------------------
__global__ __launch_bounds__(256) void k_attn_mfma(
    const unsigned short* __restrict__ QPh, const unsigned short* __restrict__ KPh,
    const unsigned short* __restrict__ VPTh, float* __restrict__ PO,
    float* __restrict__ Pl)
{
  __shared__ unsigned short plds[4][16][40];
  __shared__ float ol[4][16][32];
  __shared__ float ll[4][4][16];
  const int t = threadIdx.x;
  const int w = t >> 6, lane = t & 63;
  const int quad = lane >> 4, l16 = lane & 15;
  const int qt = blockIdx.x % 144;
  const int rest = blockIdx.x / 144;
  const int bhx = rest >> 1, ks = rest & 1;
  const int bb = bhx >> 2, h = bhx & 3;
  const int q0 = qt << 4;

  const unsigned short* vbase = VPTh + (size_t)bhx * 32 * (size_t)NK_;
  const f32x4 zf = {0.f, 0.f, 0.f, 0.f};
  f32x4 o0 = zf, o1 = zf;
  float lsum = 0.f;

  const int m8 = ks * 4 + w;
  int c0 = (108 * m8) >> 3, c1 = (108 * (m8 + 1)) >> 3;

  while (c0 < c1) {
    const int nn = c0 / 18;
    const int cend = min(c1, (nn + 1) * 18);
    const unsigned short* kb = &KPh[((size_t)(bb * 6 + nn) * K_) * 128 + h * 32];
    bf16x8 qc = *(const bf16x8*)&QPh[((size_t)(bb * 6 + nn) * Q_ + q0 + l16) * 128 + h * 32 + quad * 8];

    int kl = (c0 - nn * 18) << 5;
    bf16x8 kf0 = *(const bf16x8*)&kb[(size_t)(kl + l16) * 128 + quad * 8];
    bf16x8 kf1 = *(const bf16x8*)&kb[(size_t)(kl + 16 + l16) * 128 + quad * 8];
    const unsigned short* vb = vbase + ((size_t)c0 << 5);
    bf16x8 vf0 = *(const bf16x8*)&vb[(size_t)l16 * NK_ + quad * 8];
    bf16x8 vf1 = *(const bf16x8*)&vb[(size_t)(16 + l16) * NK_ + quad * 8];

    for (int kc = c0; kc < cend; ++kc) {
      const int kn = (kc + 1 < cend) ? kc + 1 : kc;
      const int kln = (kn - nn * 18) << 5;
      bf16x8 nk0 = *(const bf16x8*)&kb[(size_t)(kln + l16) * 128 + quad * 8];
      bf16x8 nk1 = *(const bf16x8*)&kb[(size_t)(kln + 16 + l16) * 128 + quad * 8];
      const unsigned short* vbn = vbase + ((size_t)kn << 5);
      bf16x8 nv0 = *(const bf16x8*)&vbn[(size_t)l16 * NK_ + quad * 8];
      bf16x8 nv1 = *(const bf16x8*)&vbn[(size_t)(16 + l16) * NK_ + quad * 8];

      f32x4 s0 = __builtin_amdgcn_mfma_f32_16x16x32_bf16(kf0, qc, zf, 0, 0, 0);
      f32x4 s1 = __builtin_amdgcn_mfma_f32_16x16x32_bf16(kf1, qc, zf, 0, 0, 0);

      float p00 = __expf(fminf(s0.x, 70.f)), p01 = __expf(fminf(s0.y, 70.f));
      float p02 = __expf(fminf(s0.z, 70.f)), p03 = __expf(fminf(s0.w, 70.f));
      float p10 = __expf(fminf(s1.x, 70.f)), p11 = __expf(fminf(s1.y, 70.f));
      float p12 = __expf(fminf(s1.z, 70.f)), p13 = __expf(fminf(s1.w, 70.f));
      lsum += (p00 + p01 + p02 + p03) + (p10 + p11 + p12 + p13);

      *(unsigned*)&plds[w][l16][quad * 4]          = pkbf(p00, p01);
      *(unsigned*)&plds[w][l16][quad * 4 + 2]      = pkbf(p02, p03);
      *(unsigned*)&plds[w][l16][16 + quad * 4]     = pkbf(p10, p11);
      *(unsigned*)&plds[w][l16][16 + quad * 4 + 2] = pkbf(p12, p13);
      bf16x8 pf = *(const bf16x8*)&plds[w][l16][quad * 8];

      o0 = __builtin_amdgcn_mfma_f32_16x16x32_bf16(pf, vf0, o0, 0, 0, 0);
      o1 = __builtin_amdgcn_mfma_f32_16x16x32_bf16(pf, vf1, o1, 0, 0, 0);

      kf0 = nk0; kf1 = nk1; vf0 = nv0; vf1 = nv1;
    }
    c0 = cend;
  }

  ll[w][quad][l16] = lsum;
#pragma unroll
  for (int r = 0; r < 4; ++r) {
    ol[w][quad * 4 + r][l16]      = o0[r];
    ol[w][quad * 4 + r][16 + l16] = o1[r];
  }
  __syncthreads();
  {
    const int q = t >> 4, i16 = t & 15, dd = i16 << 1;
    float a0 = 0.f, a1 = 0.f;
#pragma unroll
    for (int ww = 0; ww < 4; ++ww) { a0 += ol[ww][q][dd]; a1 += ol[ww][q][dd + 1]; }
    float2 r2; r2.x = a0; r2.y = a1;
    *(float2*)&PO[(((size_t)ks * 8 + bhx) * Q_ + q0 + q) * 32 + dd] = r2;
    if (i16 == 0) {
      float l = 0.f;
#pragma unroll
      for (int ww = 0; ww < 4; ++ww)
#pragma unroll
        for (int qq = 0; qq < 4; ++qq) l += ll[ww][qq][q];
      Pl[((size_t)ks * 8 + bhx) * Q_ + q0 + q] = l;
    }
  }
}

// ---------------------------------------------------------------------------
// Kernel C: fused ksplit-merge + out-projection (MFMA) + skip + pre-LN.
// Outputs ZB (fp32, for fc2 residual) and ZBh (bf16, fc1 A-frags).
// ---------------------------------------------------------------------------
__global__ __launch_bounds__(256) void k_proj_skip_ln(
    const float* __restrict__ PO, const float* __restrict__ Pl,
    const unsigned short* __restrict__ WTp, const float* __restrict__ bp,
    const float* __restrict__ skip, const float* __restrict__ g,
    const float* __restrict__ bln, float* __restrict__ ZB,
    unsigned short* __restrict__ ZBh)
{
  __shared__ float xs[32][132];
  __shared__ unsigned short xh[32][136];
  __shared__ float gs[128], bs[128];
  __shared__ float mu[32], rsd[32];
  const int t = threadIdx.x;
  const int row0 = blockIdx.x << 5;
  const int bb = row0 / Q_, hw0 = row0 % Q_;

  if (t < 128) { gs[t] = g[t]; bs[t] = bln[t]; }
  // merge 2-way ksplit partials, /l, -> bf16 LDS
#pragma unroll
  for (int i = 0; i < 8; ++i) {
    int idx = t + 256 * i;               // 2048 pairs
    int s = idx >> 6, c2 = (idx & 63) << 1;
    int q = hw0 + s;
    int h = c2 >> 5, dh = c2 & 31;
    size_t bq = (size_t)(bb * 4 + h) * Q_ + q;
    size_t i0 = bq * 32 + dh;
    float2 p0 = *(const float2*)&PO[i0];
    float2 p1 = *(const float2*)&PO[589824 + i0];
    float inv = 1.f / (Pl[bq] + Pl[18432 + bq]);
    *(unsigned*)&xh[s][c2] = pkbf((p0.x + p1.x) * inv, (p0.y + p1.y) * inv);
  }
  __syncthreads();
  const int w = t >> 6, lane = t & 63, quad = lane >> 4, l16 = lane & 15;
  const f32x4 zf = {0.f, 0.f, 0.f, 0.f};
  f32x4 acc[2][2] = {{zf, zf}, {zf, zf}};
#pragma unroll
  for (int kc = 0; kc < 4; ++kc) {
    bf16x8 a0 = *(const bf16x8*)&xh[l16][kc * 32 + quad * 8];
    bf16x8 a1 = *(const bf16x8*)&xh[16 + l16][kc * 32 + quad * 8];
    bf16x8 b0 = *(const bf16x8*)&WTp[(size_t)(w * 32 + l16) * 128 + kc * 32 + quad * 8];
    bf16x8 b1 = *(const bf16x8*)&WTp[(size_t)(w * 32 + 16 + l16) * 128 + kc * 32 + quad * 8];
    acc[0][0] = __builtin_amdgcn_mfma_f32_16x16x32_bf16(a0, b0, acc[0][0], 0, 0, 0);
    acc[0][1] = __builtin_amdgcn_mfma_f32_16x16x32_bf16(a0, b1, acc[0][1], 0, 0, 0);
    acc[1][0] = __builtin_amdgcn_mfma_f32_16x16x32_bf16(a1, b0, acc[1][0], 0, 0, 0);
    acc[1][1] = __builtin_amdgcn_mfma_f32_16x16x32_bf16(a1, b1, acc[1][1], 0, 0, 0);
  }
  // epilogue: + bias + skip (skip is channel-major: 4 consecutive hw = float4)
#pragma unroll
  for (int mt = 0; mt < 2; ++mt)
#pragma unroll
    for (int nt = 0; nt < 2; ++nt) {
      int col = w * 32 + nt * 16 + l16;
      float bc = bp[col];
      float4 sk = *(const float4*)&skip[((size_t)bb * 128 + col) * Q_ + hw0 + mt * 16 + quad * 4];
      xs[mt * 16 + quad * 4 + 0][col] = acc[mt][nt][0] + bc + sk.x;
      xs[mt * 16 + quad * 4 + 1][col] = acc[mt][nt][1] + bc + sk.y;
      xs[mt * 16 + quad * 4 + 2][col] = acc[mt][nt][2] + bc + sk.z;
      xs[mt * 16 + quad * 4 + 3][col] = acc[mt][nt][3] + bc + sk.w;
    }
  __syncthreads();
  {
    int s = t >> 3, l8 = t & 7;
    float sum = 0.f, sq = 0.f;
    for (int c = l8; c < 128; c += 8) { float v = xs[s][c]; sum += v; sq += v * v; }
#pragma unroll
    for (int off = 4; off > 0; off >>= 1) {
      sum += __shfl_down(sum, off, 8);
      sq  += __shfl_down(sq,  off, 8);
    }
    if (l8 == 0) {
      float mth = sum * 0.0078125f;
      float var = sq * 0.0078125f - mth * mth;
      mu[s] = mth; rsd[s] = rsqrtf(var + 1e-5f);
    }
  }
  __syncthreads();
#pragma unroll
  for (int i = 0; i < 8; ++i) {
    int idx = t + 256 * i;
    int s = idx >> 6, c2 = (idx & 63) << 1;
    float y0 = (xs[s][c2]     - mu[s]) * rsd[s] * gs[c2]     + bs[c2];
    float y1 = (xs[s][c2 + 1] - mu[s]) * rsd[s] * gs[c2 + 1] + bs[c2 + 1];
    float2 y2; y2.x = y0; y2.y = y1;
    *(float2*)&ZB[(size_t)(row0 + s) * 128 + c2] = y2;
    *(unsigned*)&ZBh[(size_t)(row0 + s) * 128 + c2] = pkbf(y0, y1);
  }
}

// ---------------------------------------------------------------------------
// Kernel D: fc1 + exact GELU, MFMA, zero input staging. grid (144, 2).
// ---------------------------------------------------------------------------
__global__ __launch_bounds__(256) void k_fc1_gelu(
    const unsigned short* __restrict__ ZBh, const unsigned short* __restrict__ W1T,
    const float* __restrict__ b1, unsigned short* __restrict__ HBh)
{
  __shared__ unsigned short xh[32][136];
  const int t = threadIdx.x;
  const int row0 = blockIdx.x << 5;
  const int jh = blockIdx.y << 7;
  const int w = t >> 6, lane = t & 63, quad = lane >> 4, l16 = lane & 15;
  const f32x4 zf = {0.f, 0.f, 0.f, 0.f};
  f32x4 acc[2][2] = {{zf, zf}, {zf, zf}};
#pragma unroll
  for (int kc = 0; kc < 4; ++kc) {
    bf16x8 a0 = *(const bf16x8*)&ZBh[(size_t)(row0 + l16) * 128 + kc * 32 + quad * 8];
    bf16x8 a1 = *(const bf16x8*)&ZBh[(size_t)(row0 + 16 + l16) * 128 + kc * 32 + quad * 8];
    bf16x8 b0 = *(const bf16x8*)&W1T[(size_t)(jh + w * 32 + l16) * 128 + kc * 32 + quad * 8];
    bf16x8 b1 = *(const bf16x8*)&W1T[(size_t)(jh + w * 32 + 16 + l16) * 128 + kc * 32 + quad * 8];
    acc[0][0] = __builtin_amdgcn_mfma_f32_16x16x32_bf16(a0, b0, acc[0][0], 0, 0, 0);
    acc[0][1] = __builtin_amdgcn_mfma_f32_16x16x32_bf16(a0, b1, acc[0][1], 0, 0, 0);
    acc[1][0] = __builtin_amdgcn_mfma_f32_16x16x32_bf16(a1, b0, acc[1][0], 0, 0, 0);
    acc[1][1] = __builtin_amdgcn_mfma_f32_16x16x32_bf16(a1, b1, acc[1][1], 0, 0, 0);
  }
#pragma unroll
  for (int mt = 0; mt < 2; ++mt)
#pragma unroll
    for (int nt = 0; nt < 2; ++nt) {
      int col = w * 32 + nt * 16 + l16;
      float bc = b1[jh + col];
#pragma unroll
      for (int r = 0; r < 4; ++r) {
        float hx = acc[mt][nt][r] + bc;
        xh[mt * 16 + quad * 4 + r][col] = f2bf(0.5f * hx * (1.f + erff(hx * 0.7071067811865476f)));
      }
    }
  __syncthreads();
#pragma unroll
  for (int i = 0; i < 2; ++i) {
    int s = i * 16 + (t >> 4), c8 = (t & 15) << 3;
    *(uint4*)&HBh[(size_t)(row0 + s) * 256 + jh + c8] = *(uint4*)&xh[s][c8];
  }
}

// ---------------------------------------------------------------------------
// Kernel E: fc2 (MFMA, K=256) + residual + post-LN + transposed store.
// ---------------------------------------------------------------------------
__global__ __launch_bounds__(256) void k_fc2_res_ln_out(
    const unsigned short* __restrict__ HBh, const unsigned short* __restrict__ W2T,
    const float* __restrict__ b2, const float* __restrict__ ZB,
    const float* __restrict__ g, const float* __restrict__ bln,
    float* __restrict__ out)
{
  __shared__ float xs[32][132];
  __shared__ float gs[128], bs[128];
  __shared__ float mu[32], rsd[32];
  const int t = threadIdx.x;
  const int row0 = blockIdx.x << 5;
  const int bb = row0 / Q_, hw0 = row0 % Q_;

  if (t < 128) { gs[t] = g[t]; bs[t] = bln[t]; }
  const int w = t >> 6, lane = t & 63, quad = lane >> 4, l16 = lane & 15;
  const f32x4 zf = {0.f, 0.f, 0.f, 0.f};
  f32x4 acc[2][2] = {{zf, zf}, {zf, zf}};
#pragma unroll
  for (int kc = 0; kc < 8; ++kc) {
    bf16x8 a0 = *(const bf16x8*)&HBh[(size_t)(row0 + l16) * 256 + kc * 32 + quad * 8];
    bf16x8 a1 = *(const bf16x8*)&HBh[(size_t)(row0 + 16 + l16) * 256 + kc * 32 + quad * 8];
    bf16x8 b0 = *(const bf16x8*)&W2T[(size_t)(w * 32 + l16) * 256 + kc * 32 + quad * 8];
    bf16x8 b1 = *(const bf16x8*)&W2T[(size_t)(w * 32 + 16 + l16) * 256 + kc * 32 + quad * 8];
    acc[0][0] = __builtin_amdgcn_mfma_f32_16x16x32_bf16(a0, b0, acc[0][0], 0, 0, 0);
    acc[0][1] = __builtin_amdgcn_mfma_f32_16x16x32_bf16(a0, b1, acc[0][1], 0, 0, 0);
    acc[1][0] = __builtin_amdgcn_mfma_f32_16x16x32_bf16(a1, b0, acc[1][0], 0, 0, 0);
    acc[1][1] = __builtin_amdgcn_mfma_f32_16x16x32_bf16(a1, b1, acc[1][1], 0, 0, 0);
  }
#pragma unroll
  for (int mt = 0; mt < 2; ++mt)
#pragma unroll
    for (int nt = 0; nt < 2; ++nt) {
      int col = w * 32 + nt * 16 + l16;
      float bc = b2[col];
#pragma unroll
      for (int r = 0; r < 4; ++r) {
        int row = mt * 16 + quad * 4 + r;
        xs[row][col] = acc[mt][nt][r] + bc + ZB[(size_t)(row0 + row) * 128 + col];
      }
    }
  __syncthreads();
  {
    int s = t >> 3, l8 = t & 7;
    float sum = 0.f, sq = 0.f;
    for (int c = l8; c < 128; c += 8) { float v = xs[s][c]; sum += v; sq += v * v; }
#pragma unroll
    for (int off = 4; off > 0; off >>= 1) {
      sum += __shfl_down(sum, off, 8);
      sq  += __shfl_down(sq,  off, 8);
    }
    if (l8 == 0) {
      float mth = sum * 0.0078125f;
      float var = sq * 0.0078125f - mth * mth;
      mu[s] = mth; rsd[s] = rsqrtf(var + 1e-5f);
    }
  }
  __syncthreads();
#pragma unroll
  for (int i = 0; i < 16; ++i) {
    int idx = t + 256 * i;
    int s = idx & 31, c = idx >> 5;
    out[(size_t)bb * (128 * (size_t)Q_) + (size_t)c * Q_ + hw0 + s] =
        (xs[s][c] - mu[s]) * rsd[s] * gs[c] + bs[c];
  }
}

// ---------------------------------------------------------------------------
extern "C" void kernel_launch(void* const* d_in, const int* in_sizes, int n_in,
                              void* d_out, int out_size, void* d_ws, size_t ws_size,
                              hipStream_t stream) {
  const float* q     = (const float*)d_in[0];
  const float* k     = (const float*)d_in[1];
  const float* v     = (const float*)d_in[2];
  const float* skip  = (const float*)d_in[3];
  const float* lnq_g = (const float*)d_in[4];
  const float* lnq_b = (const float*)d_in[5];
  const float* Wq    = (const float*)d_in[6];
  const float* bq    = (const float*)d_in[7];
  const float* lnk_g = (const float*)d_in[8];
  const float* lnk_b = (const float*)d_in[9];
  const float* Wk    = (const float*)d_in[10];
  const float* bk    = (const float*)d_in[11];
  const float* lnv_g = (const float*)d_in[12];
  const float* lnv_b = (const float*)d_in[13];
  const float* Wv    = (const float*)d_in[14];
  const float* bvv   = (const float*)d_in[15];
  const float* Wp    = (const float*)d_in[16];
  const float* bp    = (const float*)d_in[17];
  const float* pre_g = (const float*)d_in[18];
  const float* pre_b = (const float*)d_in[19];
  const float* W1    = (const float*)d_in[20];
  const float* b1    = (const float*)d_in[21];
  const float* W2    = (const float*)d_in[22];
  const float* b2    = (const float*)d_in[23];
  const float* post_g= (const float*)d_in[24];
  const float* post_b= (const float*)d_in[25];
  float* out = (float*)d_out;

  // Workspace layout (21.6 MB total; R0 established >= 23.6 MB available)
  unsigned short* QPh  = (unsigned short*)d_ws;        // 3,538,944 h
  unsigned short* KPh  = QPh + 3538944;                //   884,736 h
  unsigned short* VPTh = KPh + 884736;                 //   884,736 h
  float* PO  = (float*)(VPTh + 884736);                // 1,179,648 f
  float* Pl  = PO + 1179648;                           //    36,864 f
  float* ZB  = Pl + 36864;                             //   589,824 f
  unsigned short* WTq = (unsigned short*)(ZB + 589824);//    16,384 h
  unsigned short* WTk = WTq + 16384;                   //    16,384 h
  unsigned short* WTv = WTk + 16384;                   //    16,384 h
  unsigned short* WTp = WTv + 16384;                   //    16,384 h
  unsigned short* WT1 = WTp + 16384;                   //    32,768 h
  unsigned short* WT2 = WT1 + 32768;                   //    32,768 h
  unsigned short* ZBh = WT2 + 32768;                   //   589,824 h
  unsigned short* HBh = ZBh + 589824;                  // 1,179,648 h

  k_prep_wt<<<dim3(128), dim3(256), 0, stream>>>(Wq, Wk, Wv, Wp, W1, W2,
                                                 WTq, WTk, WTv, WTp, WT1, WT2);
  k_ln_proj_qk<<<dim3(864), dim3(256), 0, stream>>>(q, lnq_g, lnq_b, WTq, bq, QPh, Q_, SCALE_);
  k_ln_proj_qk<<<dim3(216), dim3(256), 0, stream>>>(k, lnk_g, lnk_b, WTk, bk, KPh, K_, 1.0f);
  k_ln_proj_vT<<<dim3(216), dim3(256), 0, stream>>>(v, lnv_g, lnv_b, WTv, bvv, VPTh);
  k_attn_mfma<<<dim3(2304), dim3(256), 0, stream>>>(QPh, KPh, VPTh, PO, Pl);
  k_proj_skip_ln<<<dim3(144), dim3(256), 0, stream>>>(PO, Pl, WTp, bp, skip, pre_g, pre_b, ZB, ZBh);
  k_fc1_gelu<<<dim3(144, 2), dim3(256), 0, stream>>>(ZBh, WT1, b1, HBh);
  k_fc2_res_ln_out<<<dim3(144), dim3(256), 0, stream>>>(HBh, WT2, b2, ZB, post_g, post_b, out);
}

// Round 5
// 176.676 us; speedup vs baseline: 3.7145x; 1.2275x over previous
//
#include <hip/hip_runtime.h>
#include <cmath>

// Shapes (fixed for this problem)
#define B_    2
#define N_    6
#define D_    128
#define Q_    2304      // 48*48
#define K_    576       // 24*24
#define NK_   3456      // N_*K_
#define HEADS_ 4
#define DH_   32
#define SCALE_ 0.17677669529663687f  // 1/sqrt(32)

typedef __attribute__((ext_vector_type(8))) short bf16x8;
typedef __attribute__((ext_vector_type(4))) float f32x4;

static __device__ __forceinline__ unsigned short f2bf(float f) {
  union { float f; unsigned u; } x; x.f = f;
  unsigned u = x.u + 0x7fffu + ((x.u >> 16) & 1u);   // RNE
  return (unsigned short)(u >> 16);
}
static __device__ __forceinline__ unsigned pkbf(float a, float b) {
  return (unsigned)f2bf(a) | ((unsigned)f2bf(b) << 16);
}

// ---------------------------------------------------------------------------
// Kernel P: transpose+convert all weights to bf16 WT[n][k] (MFMA B-frag
// layout). 128 blocks, one 32x32 tile each.
// ---------------------------------------------------------------------------
__global__ __launch_bounds__(256) void k_prep_wt(
    const float* __restrict__ Wq, const float* __restrict__ Wk,
    const float* __restrict__ Wv, const float* __restrict__ Wp,
    const float* __restrict__ W1, const float* __restrict__ W2,
    unsigned short* __restrict__ WTq, unsigned short* __restrict__ WTk,
    unsigned short* __restrict__ WTv, unsigned short* __restrict__ WTp,
    unsigned short* __restrict__ WT1, unsigned short* __restrict__ WT2)
{
  __shared__ float tile[32][33];
  const int wb = blockIdx.x, t = threadIdx.x;
  const float* src; unsigned short* dst; int Kd, J, tl;
  if      (wb < 16) { src = Wq; dst = WTq; Kd = 128; J = 128; tl = wb; }
  else if (wb < 32) { src = Wk; dst = WTk; Kd = 128; J = 128; tl = wb - 16; }
  else if (wb < 48) { src = Wv; dst = WTv; Kd = 128; J = 128; tl = wb - 32; }
  else if (wb < 64) { src = Wp; dst = WTp; Kd = 128; J = 128; tl = wb - 48; }
  else if (wb < 96) { src = W1; dst = WT1; Kd = 128; J = 256; tl = wb - 64; }
  else              { src = W2; dst = WT2; Kd = 256; J = 128; tl = wb - 96; }
  const int njt = J >> 5;
  const int tj = tl % njt, tk = tl / njt;
#pragma unroll
  for (int i = 0; i < 4; ++i) {
    int idx = t + 256 * i;
    int r = idx >> 5, c = idx & 31;
    tile[r][c] = src[(size_t)(tk * 32 + r) * J + tj * 32 + c];
  }
  __syncthreads();
#pragma unroll
  for (int i = 0; i < 2; ++i) {
    int idx = t + 256 * i;               // 512 pairs
    int rr = idx >> 4, c2 = (idx & 15) << 1;
    *(unsigned*)&dst[(size_t)(tj * 32 + rr) * Kd + tk * 32 + c2] =
        pkbf(tile[c2][rr], tile[c2 + 1][rr]);
  }
}

// ---------------------------------------------------------------------------
// Kernel A: fused q/k/v LN + MFMA projection (single dispatch, 1296 blocks).
// blocks [0,864): q -> QPh (row-major, *SCALE); [864,1080): k -> KPh;
// [1080,1296): v -> VPTh transposed [b][h][dh][NK].
// ---------------------------------------------------------------------------
__global__ __launch_bounds__(256) void k_ln_proj_all(
    const float* __restrict__ qin, const float* __restrict__ kin,
    const float* __restrict__ vin,
    const float* __restrict__ lnq_g, const float* __restrict__ lnq_b,
    const float* __restrict__ lnk_g, const float* __restrict__ lnk_b,
    const float* __restrict__ lnv_g, const float* __restrict__ lnv_b,
    const unsigned short* __restrict__ WTq, const unsigned short* __restrict__ WTk,
    const unsigned short* __restrict__ WTv,
    const float* __restrict__ bq, const float* __restrict__ bk,
    const float* __restrict__ bv,
    unsigned short* __restrict__ QPh, unsigned short* __restrict__ KPh,
    unsigned short* __restrict__ VPTh)
{
  __shared__ float xs[32][132];
  __shared__ unsigned short xh[32][136];
  __shared__ float gs[128], bs[128];
  __shared__ float mu[32], rsd[32];
  const int t = threadIdx.x;
  const int bid = blockIdx.x;

  const float* x; const unsigned short* WT; const float* g; const float* bl;
  const float* bias; int S, blk, mode; float osc;
  if (bid < 864)       { mode = 0; blk = bid;        x = qin; WT = WTq; g = lnq_g; bl = lnq_b; bias = bq; S = Q_; osc = SCALE_; }
  else if (bid < 1080) { mode = 0; blk = bid - 864;  x = kin; WT = WTk; g = lnk_g; bl = lnk_b; bias = bk; S = K_; osc = 1.0f; }
  else                 { mode = 1; blk = bid - 1080; x = vin; WT = WTv; g = lnv_g; bl = lnv_b; bias = bv; S = K_; osc = 1.0f; }
  const int ntile = S >> 5;
  const int o  = blk / ntile;
  const int s0 = (blk % ntile) << 5;

  if (t < 128) { gs[t] = g[t]; bs[t] = bl[t]; }
  const float* xb = x + (size_t)o * 128 * (size_t)S + s0;
#pragma unroll
  for (int i = 0; i < 16; ++i) {
    int idx = t + 256 * i;
    int c = idx >> 5, s = idx & 31;
    xs[s][c] = xb[(size_t)c * S + s];
  }
  __syncthreads();
  {
    int s = t >> 3, l8 = t & 7;
    float sum = 0.f, sq = 0.f;
    for (int c = l8; c < 128; c += 8) { float v = xs[s][c]; sum += v; sq += v * v; }
#pragma unroll
    for (int off = 4; off > 0; off >>= 1) {
      sum += __shfl_down(sum, off, 8);
      sq  += __shfl_down(sq,  off, 8);
    }
    if (l8 == 0) {
      float mth = sum * 0.0078125f;
      float var = sq * 0.0078125f - mth * mth;
      mu[s] = mth; rsd[s] = rsqrtf(var + 1e-5f);
    }
  }
  __syncthreads();
#pragma unroll
  for (int i = 0; i < 8; ++i) {
    int idx = t + 256 * i;               // 2048 pairs
    int s = idx >> 6, c2 = (idx & 63) << 1;
    float y0 = (xs[s][c2]     - mu[s]) * rsd[s] * gs[c2]     + bs[c2];
    float y1 = (xs[s][c2 + 1] - mu[s]) * rsd[s] * gs[c2 + 1] + bs[c2 + 1];
    *(unsigned*)&xh[s][c2] = pkbf(y0, y1);
  }
  __syncthreads();
  const int w = t >> 6, lane = t & 63, quad = lane >> 4, l16 = lane & 15;
  const f32x4 zf = {0.f, 0.f, 0.f, 0.f};
  f32x4 acc[2][2] = {{zf, zf}, {zf, zf}};
#pragma unroll
  for (int kc = 0; kc < 4; ++kc) {
    bf16x8 a0 = *(const bf16x8*)&xh[l16][kc * 32 + quad * 8];
    bf16x8 a1 = *(const bf16x8*)&xh[16 + l16][kc * 32 + quad * 8];
    bf16x8 b0 = *(const bf16x8*)&WT[(size_t)(w * 32 + l16) * 128 + kc * 32 + quad * 8];
    bf16x8 b1 = *(const bf16x8*)&WT[(size_t)(w * 32 + 16 + l16) * 128 + kc * 32 + quad * 8];
    acc[0][0] = __builtin_amdgcn_mfma_f32_16x16x32_bf16(a0, b0, acc[0][0], 0, 0, 0);
    acc[0][1] = __builtin_amdgcn_mfma_f32_16x16x32_bf16(a0, b1, acc[0][1], 0, 0, 0);
    acc[1][0] = __builtin_amdgcn_mfma_f32_16x16x32_bf16(a1, b0, acc[1][0], 0, 0, 0);
    acc[1][1] = __builtin_amdgcn_mfma_f32_16x16x32_bf16(a1, b1, acc[1][1], 0, 0, 0);
  }
  if (mode == 0) {
    unsigned short* outh = (bid < 864) ? QPh : KPh;
    __syncthreads();                      // xh reused as output staging
#pragma unroll
    for (int mt = 0; mt < 2; ++mt)
#pragma unroll
      for (int nt = 0; nt < 2; ++nt) {
        int col = w * 32 + nt * 16 + l16;
        float bc = bias[col];
#pragma unroll
        for (int r = 0; r < 4; ++r)
          xh[mt * 16 + quad * 4 + r][col] = f2bf((acc[mt][nt][r] + bc) * osc);
      }
    __syncthreads();
#pragma unroll
    for (int i = 0; i < 2; ++i) {
      int s = i * 16 + (t >> 4), c8 = (t & 15) << 3;
      *(uint4*)&outh[((size_t)o * S + s0 + s) * 128 + c8] = *(uint4*)&xh[s][c8];
    }
  } else {
    const int b = o / 6, n = o % 6;
#pragma unroll
    for (int mt = 0; mt < 2; ++mt)
#pragma unroll
      for (int nt = 0; nt < 2; ++nt) {
        int col = w * 32 + nt * 16 + l16;
        int hh = col >> 5, dh = col & 31;
        float bc = bias[col];
        ushort4 pk;
        pk.x = f2bf(acc[mt][nt][0] + bc); pk.y = f2bf(acc[mt][nt][1] + bc);
        pk.z = f2bf(acc[mt][nt][2] + bc); pk.w = f2bf(acc[mt][nt][3] + bc);
        int s = n * 576 + s0 + mt * 16 + quad * 4;
        *(ushort4*)&VPTh[((size_t)(b * 4 + hh) * 32 + dh) * (size_t)NK_ + s] = pk;
      }
  }
}

// ---------------------------------------------------------------------------
// Kernel B: MFMA flash attention, no-max softmax, split-K 2-way,
// TWO independent q-tiles per wave (32 queries/block) for latency hiding.
// Grid: 72 qpos x 8 bh x 2 ks = 1152 blocks, 4 waves each.
// ---------------------------------------------------------------------------
__global__ __launch_bounds__(256) void k_attn_mfma(
    const unsigned short* __restrict__ QPh, const unsigned short* __restrict__ KPh,
    const unsigned short* __restrict__ VPTh, float* __restrict__ PO,
    float* __restrict__ Pl)
{
  __shared__ unsigned short plds[4][2][16][40];   // per-wave, per-tile P
  __shared__ float ol[4][16][32];
  __shared__ float ll[4][2][4][16];
  const int t = threadIdx.x;
  const int w = t >> 6, lane = t & 63;
  const int quad = lane >> 4, l16 = lane & 15;
  const int qt = blockIdx.x % 72;
  const int rest = blockIdx.x / 72;
  const int bhx = rest >> 1, ks = rest & 1;
  const int bb = bhx >> 2, h = bhx & 3;
  const int q0 = qt << 5;

  const unsigned short* vbase = VPTh + (size_t)bhx * 32 * (size_t)NK_;
  const f32x4 zf = {0.f, 0.f, 0.f, 0.f};
  f32x4 o00 = zf, o01 = zf, o10 = zf, o11 = zf;
  float lsum0 = 0.f, lsum1 = 0.f;

  const int m8 = ks * 4 + w;
  int c0 = (108 * m8) >> 3, c1 = (108 * (m8 + 1)) >> 3;   // 13-14 chunks

  while (c0 < c1) {
    const int nn = c0 / 18;
    const int cend = min(c1, (nn + 1) * 18);
    const unsigned short* kb = &KPh[((size_t)(bb * 6 + nn) * K_) * 128 + h * 32];
    const unsigned short* qb = &QPh[((size_t)(bb * 6 + nn) * Q_ + q0) * 128 + h * 32];
    bf16x8 qc0 = *(const bf16x8*)&qb[(size_t)l16 * 128 + quad * 8];
    bf16x8 qc1 = *(const bf16x8*)&qb[(size_t)(16 + l16) * 128 + quad * 8];

    int kl = (c0 - nn * 18) << 5;
    bf16x8 kf0 = *(const bf16x8*)&kb[(size_t)(kl + l16) * 128 + quad * 8];
    bf16x8 kf1 = *(const bf16x8*)&kb[(size_t)(kl + 16 + l16) * 128 + quad * 8];
    const unsigned short* vb = vbase + ((size_t)c0 << 5);
    bf16x8 vf0 = *(const bf16x8*)&vb[(size_t)l16 * NK_ + quad * 8];
    bf16x8 vf1 = *(const bf16x8*)&vb[(size_t)(16 + l16) * NK_ + quad * 8];

    for (int kc = c0; kc < cend; ++kc) {
      const int kn = (kc + 1 < cend) ? kc + 1 : kc;
      const int kln = (kn - nn * 18) << 5;
      bf16x8 nk0 = *(const bf16x8*)&kb[(size_t)(kln + l16) * 128 + quad * 8];
      bf16x8 nk1 = *(const bf16x8*)&kb[(size_t)(kln + 16 + l16) * 128 + quad * 8];
      const unsigned short* vbn = vbase + ((size_t)kn << 5);
      bf16x8 nv0 = *(const bf16x8*)&vbn[(size_t)l16 * NK_ + quad * 8];
      bf16x8 nv1 = *(const bf16x8*)&vbn[(size_t)(16 + l16) * NK_ + quad * 8];

      // S^T tiles for both q-tiles (shared K fragments)
      f32x4 s00 = __builtin_amdgcn_mfma_f32_16x16x32_bf16(kf0, qc0, zf, 0, 0, 0);
      f32x4 s01 = __builtin_amdgcn_mfma_f32_16x16x32_bf16(kf1, qc0, zf, 0, 0, 0);
      f32x4 s10 = __builtin_amdgcn_mfma_f32_16x16x32_bf16(kf0, qc1, zf, 0, 0, 0);
      f32x4 s11 = __builtin_amdgcn_mfma_f32_16x16x32_bf16(kf1, qc1, zf, 0, 0, 0);

      float a00 = __expf(fminf(s00.x, 70.f)), a01 = __expf(fminf(s00.y, 70.f));
      float a02 = __expf(fminf(s00.z, 70.f)), a03 = __expf(fminf(s00.w, 70.f));
      float a10 = __expf(fminf(s01.x, 70.f)), a11 = __expf(fminf(s01.y, 70.f));
      float a12 = __expf(fminf(s01.z, 70.f)), a13 = __expf(fminf(s01.w, 70.f));
      lsum0 += (a00 + a01 + a02 + a03) + (a10 + a11 + a12 + a13);
      float b00 = __expf(fminf(s10.x, 70.f)), b01 = __expf(fminf(s10.y, 70.f));
      float b02 = __expf(fminf(s10.z, 70.f)), b03 = __expf(fminf(s10.w, 70.f));
      float b10 = __expf(fminf(s11.x, 70.f)), b11 = __expf(fminf(s11.y, 70.f));
      float b12 = __expf(fminf(s11.z, 70.f)), b13 = __expf(fminf(s11.w, 70.f));
      lsum1 += (b00 + b01 + b02 + b03) + (b10 + b11 + b12 + b13);

      *(unsigned*)&plds[w][0][l16][quad * 4]          = pkbf(a00, a01);
      *(unsigned*)&plds[w][0][l16][quad * 4 + 2]      = pkbf(a02, a03);
      *(unsigned*)&plds[w][0][l16][16 + quad * 4]     = pkbf(a10, a11);
      *(unsigned*)&plds[w][0][l16][16 + quad * 4 + 2] = pkbf(a12, a13);
      *(unsigned*)&plds[w][1][l16][quad * 4]          = pkbf(b00, b01);
      *(unsigned*)&plds[w][1][l16][quad * 4 + 2]      = pkbf(b02, b03);
      *(unsigned*)&plds[w][1][l16][16 + quad * 4]     = pkbf(b10, b11);
      *(unsigned*)&plds[w][1][l16][16 + quad * 4 + 2] = pkbf(b12, b13);
      bf16x8 pf0 = *(const bf16x8*)&plds[w][0][l16][quad * 8];
      bf16x8 pf1 = *(const bf16x8*)&plds[w][1][l16][quad * 8];

      o00 = __builtin_amdgcn_mfma_f32_16x16x32_bf16(pf0, vf0, o00, 0, 0, 0);
      o01 = __builtin_amdgcn_mfma_f32_16x16x32_bf16(pf0, vf1, o01, 0, 0, 0);
      o10 = __builtin_amdgcn_mfma_f32_16x16x32_bf16(pf1, vf0, o10, 0, 0, 0);
      o11 = __builtin_amdgcn_mfma_f32_16x16x32_bf16(pf1, vf1, o11, 0, 0, 0);

      kf0 = nk0; kf1 = nk1; vf0 = nv0; vf1 = nv1;
    }
    c0 = cend;
  }

  ll[w][0][quad][l16] = lsum0;
  ll[w][1][quad][l16] = lsum1;
#pragma unroll
  for (int tt = 0; tt < 2; ++tt) {
    __syncthreads();
    f32x4 t0 = tt ? o10 : o00;
    f32x4 t1 = tt ? o11 : o01;
#pragma unroll
    for (int r = 0; r < 4; ++r) {
      ol[w][quad * 4 + r][l16]      = t0[r];
      ol[w][quad * 4 + r][16 + l16] = t1[r];
    }
    __syncthreads();
    const int q = t >> 4, i16 = t & 15, dd = i16 << 1;
    float a0 = 0.f, a1 = 0.f;
#pragma unroll
    for (int ww = 0; ww < 4; ++ww) { a0 += ol[ww][q][dd]; a1 += ol[ww][q][dd + 1]; }
    float2 r2; r2.x = a0; r2.y = a1;
    *(float2*)&PO[(((size_t)ks * 8 + bhx) * Q_ + q0 + tt * 16 + q) * 32 + dd] = r2;
    if (i16 == 0) {
      float l = 0.f;
#pragma unroll
      for (int ww = 0; ww < 4; ++ww)
#pragma unroll
        for (int qq = 0; qq < 4; ++qq) l += ll[ww][tt][qq][q];
      Pl[((size_t)ks * 8 + bhx) * Q_ + q0 + tt * 16 + q] = l;
    }
  }
}

// ---------------------------------------------------------------------------
// Kernel C (fused tail): ksplit-merge + out-proj + skip + preLN + fc1 + GELU
// + fc2 + residual + postLN + transposed store. All row-local; everything
// between stages stays in LDS. 144 blocks x 32 rows.
// ---------------------------------------------------------------------------
__global__ __launch_bounds__(256) void k_tail(
    const float* __restrict__ PO, const float* __restrict__ Pl,
    const unsigned short* __restrict__ WTp, const float* __restrict__ bp,
    const float* __restrict__ skip,
    const float* __restrict__ pre_g, const float* __restrict__ pre_b,
    const unsigned short* __restrict__ WT1, const float* __restrict__ b1,
    const unsigned short* __restrict__ WT2, const float* __restrict__ b2,
    const float* __restrict__ post_g, const float* __restrict__ post_b,
    float* __restrict__ out)
{
  __shared__ float xs[32][132];            // fp32 stage (proj out, z, fc2 out)
  __shared__ unsigned short xh[32][136];   // bf16 A-frags (merged AO, then z)
  __shared__ unsigned short hb[32][264];   // fc1 activations bf16
  __shared__ float g1s[128], b1s[128], g2s[128], b2s[128];
  __shared__ float mu[32], rsd[32];
  const int t = threadIdx.x;
  const int row0 = blockIdx.x << 5;
  const int bb = row0 / Q_, hw0 = row0 % Q_;
  const int w = t >> 6, lane = t & 63, quad = lane >> 4, l16 = lane & 15;
  const f32x4 zf = {0.f, 0.f, 0.f, 0.f};

  if (t < 128) { g1s[t] = pre_g[t]; b1s[t] = pre_b[t]; g2s[t] = post_g[t]; b2s[t] = post_b[t]; }
  // --- stage 1: merge ksplit partials -> bf16 A-frags in xh
#pragma unroll
  for (int i = 0; i < 8; ++i) {
    int idx = t + 256 * i;               // 2048 pairs
    int s = idx >> 6, c2 = (idx & 63) << 1;
    int q = hw0 + s;
    int h = c2 >> 5, dh = c2 & 31;
    size_t bq = (size_t)(bb * 4 + h) * Q_ + q;
    size_t i0 = bq * 32 + dh;
    float2 p0 = *(const float2*)&PO[i0];
    float2 p1 = *(const float2*)&PO[589824 + i0];
    float inv = 1.f / (Pl[bq] + Pl[18432 + bq]);
    *(unsigned*)&xh[s][c2] = pkbf((p0.x + p1.x) * inv, (p0.y + p1.y) * inv);
  }
  __syncthreads();
  // --- stage 2: out-projection MFMA
  {
    f32x4 acc[2][2] = {{zf, zf}, {zf, zf}};
#pragma unroll
    for (int kc = 0; kc < 4; ++kc) {
      bf16x8 a0 = *(const bf16x8*)&xh[l16][kc * 32 + quad * 8];
      bf16x8 a1 = *(const bf16x8*)&xh[16 + l16][kc * 32 + quad * 8];
      bf16x8 b0 = *(const bf16x8*)&WTp[(size_t)(w * 32 + l16) * 128 + kc * 32 + quad * 8];
      bf16x8 b1v = *(const bf16x8*)&WTp[(size_t)(w * 32 + 16 + l16) * 128 + kc * 32 + quad * 8];
      acc[0][0] = __builtin_amdgcn_mfma_f32_16x16x32_bf16(a0, b0, acc[0][0], 0, 0, 0);
      acc[0][1] = __builtin_amdgcn_mfma_f32_16x16x32_bf16(a0, b1v, acc[0][1], 0, 0, 0);
      acc[1][0] = __builtin_amdgcn_mfma_f32_16x16x32_bf16(a1, b0, acc[1][0], 0, 0, 0);
      acc[1][1] = __builtin_amdgcn_mfma_f32_16x16x32_bf16(a1, b1v, acc[1][1], 0, 0, 0);
    }
#pragma unroll
    for (int mt = 0; mt < 2; ++mt)
#pragma unroll
      for (int nt = 0; nt < 2; ++nt) {
        int col = w * 32 + nt * 16 + l16;
        float bc = bp[col];
        float4 sk = *(const float4*)&skip[((size_t)bb * 128 + col) * Q_ + hw0 + mt * 16 + quad * 4];
        xs[mt * 16 + quad * 4 + 0][col] = acc[mt][nt][0] + bc + sk.x;
        xs[mt * 16 + quad * 4 + 1][col] = acc[mt][nt][1] + bc + sk.y;
        xs[mt * 16 + quad * 4 + 2][col] = acc[mt][nt][2] + bc + sk.z;
        xs[mt * 16 + quad * 4 + 3][col] = acc[mt][nt][3] + bc + sk.w;
      }
  }
  __syncthreads();
  // --- stage 3: preLN (z kept fp32 in xs, bf16 in xh)
  {
    int s = t >> 3, l8 = t & 7;
    float sum = 0.f, sq = 0.f;
    for (int c = l8; c < 128; c += 8) { float v = xs[s][c]; sum += v; sq += v * v; }
#pragma unroll
    for (int off = 4; off > 0; off >>= 1) {
      sum += __shfl_down(sum, off, 8);
      sq  += __shfl_down(sq,  off, 8);
    }
    if (l8 == 0) {
      float mth = sum * 0.0078125f;
      float var = sq * 0.0078125f - mth * mth;
      mu[s] = mth; rsd[s] = rsqrtf(var + 1e-5f);
    }
  }
  __syncthreads();
#pragma unroll
  for (int i = 0; i < 8; ++i) {
    int idx = t + 256 * i;
    int s = idx >> 6, c2 = (idx & 63) << 1;
    float y0 = (xs[s][c2]     - mu[s]) * rsd[s] * g1s[c2]     + b1s[c2];
    float y1 = (xs[s][c2 + 1] - mu[s]) * rsd[s] * g1s[c2 + 1] + b1s[c2 + 1];
    xs[s][c2] = y0; xs[s][c2 + 1] = y1;
    *(unsigned*)&xh[s][c2] = pkbf(y0, y1);
  }
  __syncthreads();
  // --- stage 4: fc1 + GELU (two column halves), results bf16 in hb
#pragma unroll
  for (int jh = 0; jh < 256; jh += 128) {
    f32x4 acc[2][2] = {{zf, zf}, {zf, zf}};
#pragma unroll
    for (int kc = 0; kc < 4; ++kc) {
      bf16x8 a0 = *(const bf16x8*)&xh[l16][kc * 32 + quad * 8];
      bf16x8 a1 = *(const bf16x8*)&xh[16 + l16][kc * 32 + quad * 8];
      bf16x8 b0 = *(const bf16x8*)&WT1[(size_t)(jh + w * 32 + l16) * 128 + kc * 32 + quad * 8];
      bf16x8 b1v = *(const bf16x8*)&WT1[(size_t)(jh + w * 32 + 16 + l16) * 128 + kc * 32 + quad * 8];
      acc[0][0] = __builtin_amdgcn_mfma_f32_16x16x32_bf16(a0, b0, acc[0][0], 0, 0, 0);
      acc[0][1] = __builtin_amdgcn_mfma_f32_16x16x32_bf16(a0, b1v, acc[0][1], 0, 0, 0);
      acc[1][0] = __builtin_amdgcn_mfma_f32_16x16x32_bf16(a1, b0, acc[1][0], 0, 0, 0);
      acc[1][1] = __builtin_amdgcn_mfma_f32_16x16x32_bf16(a1, b1v, acc[1][1], 0, 0, 0);
    }
#pragma unroll
    for (int mt = 0; mt < 2; ++mt)
#pragma unroll
      for (int nt = 0; nt < 2; ++nt) {
        int col = w * 32 + nt * 16 + l16;
        float bc = b1[jh + col];
#pragma unroll
        for (int r = 0; r < 4; ++r) {
          float hx = acc[mt][nt][r] + bc;
          hb[mt * 16 + quad * 4 + r][jh + col] =
              f2bf(0.5f * hx * (1.f + erff(hx * 0.7071067811865476f)));
        }
      }
  }
  __syncthreads();
  // --- stage 5: fc2 (K=256) + residual z
  {
    f32x4 acc[2][2] = {{zf, zf}, {zf, zf}};
#pragma unroll
    for (int kc = 0; kc < 8; ++kc) {
      bf16x8 a0 = *(const bf16x8*)&hb[l16][kc * 32 + quad * 8];
      bf16x8 a1 = *(const bf16x8*)&hb[16 + l16][kc * 32 + quad * 8];
      bf16x8 b0 = *(const bf16x8*)&WT2[(size_t)(w * 32 + l16) * 256 + kc * 32 + quad * 8];
      bf16x8 b1v = *(const bf16x8*)&WT2[(size_t)(w * 32 + 16 + l16) * 256 + kc * 32 + quad * 8];
      acc[0][0] = __builtin_amdgcn_mfma_f32_16x16x32_bf16(a0, b0, acc[0][0], 0, 0, 0);
      acc[0][1] = __builtin_amdgcn_mfma_f32_16x16x32_bf16(a0, b1v, acc[0][1], 0, 0, 0);
      acc[1][0] = __builtin_amdgcn_mfma_f32_16x16x32_bf16(a1, b0, acc[1][0], 0, 0, 0);
      acc[1][1] = __builtin_amdgcn_mfma_f32_16x16x32_bf16(a1, b1v, acc[1][1], 0, 0, 0);
    }
#pragma unroll
    for (int mt = 0; mt < 2; ++mt)
#pragma unroll
      for (int nt = 0; nt < 2; ++nt) {
        int col = w * 32 + nt * 16 + l16;
        float bc = b2[col];
#pragma unroll
        for (int r = 0; r < 4; ++r) {
          int row = mt * 16 + quad * 4 + r;
          xs[row][col] = acc[mt][nt][r] + bc + xs[row][col];
        }
      }
  }
  __syncthreads();
  // --- stage 6: postLN + transposed store
  {
    int s = t >> 3, l8 = t & 7;
    float sum = 0.f, sq = 0.f;
    for (int c = l8; c < 128; c += 8) { float v = xs[s][c]; sum += v; sq += v * v; }
#pragma unroll
    for (int off = 4; off > 0; off >>= 1) {
      sum += __shfl_down(sum, off, 8);
      sq  += __shfl_down(sq,  off, 8);
    }
    if (l8 == 0) {
      float mth = sum * 0.0078125f;
      float var = sq * 0.0078125f - mth * mth;
      mu[s] = mth; rsd[s] = rsqrtf(var + 1e-5f);
    }
  }
  __syncthreads();
#pragma unroll
  for (int i = 0; i < 16; ++i) {
    int idx = t + 256 * i;
    int s = idx & 31, c = idx >> 5;
    out[(size_t)bb * (128 * (size_t)Q_) + (size_t)c * Q_ + hw0 + s] =
        (xs[s][c] - mu[s]) * rsd[s] * g2s[c] + b2s[c];
  }
}

// ---------------------------------------------------------------------------
extern "C" void kernel_launch(void* const* d_in, const int* in_sizes, int n_in,
                              void* d_out, int out_size, void* d_ws, size_t ws_size,
                              hipStream_t stream) {
  const float* q     = (const float*)d_in[0];
  const float* k     = (const float*)d_in[1];
  const float* v     = (const float*)d_in[2];
  const float* skip  = (const float*)d_in[3];
  const float* lnq_g = (const float*)d_in[4];
  const float* lnq_b = (const float*)d_in[5];
  const float* Wq    = (const float*)d_in[6];
  const float* bq    = (const float*)d_in[7];
  const float* lnk_g = (const float*)d_in[8];
  const float* lnk_b = (const float*)d_in[9];
  const float* Wk    = (const float*)d_in[10];
  const float* bk    = (const float*)d_in[11];
  const float* lnv_g = (const float*)d_in[12];
  const float* lnv_b = (const float*)d_in[13];
  const float* Wv    = (const float*)d_in[14];
  const float* bvv   = (const float*)d_in[15];
  const float* Wp    = (const float*)d_in[16];
  const float* bp    = (const float*)d_in[17];
  const float* pre_g = (const float*)d_in[18];
  const float* pre_b = (const float*)d_in[19];
  const float* W1    = (const float*)d_in[20];
  const float* b1    = (const float*)d_in[21];
  const float* W2    = (const float*)d_in[22];
  const float* b2    = (const float*)d_in[23];
  const float* post_g= (const float*)d_in[24];
  const float* post_b= (const float*)d_in[25];
  float* out = (float*)d_out;

  // Workspace layout (~15.7 MB)
  unsigned short* QPh  = (unsigned short*)d_ws;        // 3,538,944 h
  unsigned short* KPh  = QPh + 3538944;                //   884,736 h
  unsigned short* VPTh = KPh + 884736;                 //   884,736 h
  float* PO  = (float*)(VPTh + 884736);                // 1,179,648 f
  float* Pl  = PO + 1179648;                           //    36,864 f
  unsigned short* WTq = (unsigned short*)(Pl + 36864); //    16,384 h
  unsigned short* WTk = WTq + 16384;                   //    16,384 h
  unsigned short* WTv = WTk + 16384;                   //    16,384 h
  unsigned short* WTp = WTv + 16384;                   //    16,384 h
  unsigned short* WT1 = WTp + 16384;                   //    32,768 h
  unsigned short* WT2 = WT1 + 32768;                   //    32,768 h

  k_prep_wt<<<dim3(128), dim3(256), 0, stream>>>(Wq, Wk, Wv, Wp, W1, W2,
                                                 WTq, WTk, WTv, WTp, WT1, WT2);
  k_ln_proj_all<<<dim3(1296), dim3(256), 0, stream>>>(
      q, k, v, lnq_g, lnq_b, lnk_g, lnk_b, lnv_g, lnv_b,
      WTq, WTk, WTv, bq, bk, bvv, QPh, KPh, VPTh);
  k_attn_mfma<<<dim3(1152), dim3(256), 0, stream>>>(QPh, KPh, VPTh, PO, Pl);
  k_tail<<<dim3(144), dim3(256), 0, stream>>>(PO, Pl, WTp, bp, skip,
                                              pre_g, pre_b, WT1, b1, WT2, b2,
                                              post_g, post_b, out);
}

// Round 6
// 176.486 us; speedup vs baseline: 3.7185x; 1.0011x over previous
//
#include <hip/hip_runtime.h>
#include <cmath>

// Shapes (fixed for this problem)
#define B_    2
#define N_    6
#define D_    128
#define Q_    2304      // 48*48
#define K_    576       // 24*24
#define NK_   3456      // N_*K_
#define HEADS_ 4
#define DH_   32
#define SCALE_ 0.17677669529663687f  // 1/sqrt(32)

typedef __attribute__((ext_vector_type(8))) short bf16x8;
typedef __attribute__((ext_vector_type(4))) float f32x4;

static __device__ __forceinline__ unsigned short f2bf(float f) {
  union { float f; unsigned u; } x; x.f = f;
  unsigned u = x.u + 0x7fffu + ((x.u >> 16) & 1u);   // RNE
  return (unsigned short)(u >> 16);
}
static __device__ __forceinline__ unsigned pkbf(float a, float b) {
  return (unsigned)f2bf(a) | ((unsigned)f2bf(b) << 16);
}

// ---------------------------------------------------------------------------
// Kernel P: transpose+convert all weights to bf16 WT[n][k] (MFMA B-frag
// layout). 128 blocks, one 32x32 tile each.
// ---------------------------------------------------------------------------
__global__ __launch_bounds__(256) void k_prep_wt(
    const float* __restrict__ Wq, const float* __restrict__ Wk,
    const float* __restrict__ Wv, const float* __restrict__ Wp,
    const float* __restrict__ W1, const float* __restrict__ W2,
    unsigned short* __restrict__ WTq, unsigned short* __restrict__ WTk,
    unsigned short* __restrict__ WTv, unsigned short* __restrict__ WTp,
    unsigned short* __restrict__ WT1, unsigned short* __restrict__ WT2)
{
  __shared__ float tile[32][33];
  const int wb = blockIdx.x, t = threadIdx.x;
  const float* src; unsigned short* dst; int Kd, J, tl;
  if      (wb < 16) { src = Wq; dst = WTq; Kd = 128; J = 128; tl = wb; }
  else if (wb < 32) { src = Wk; dst = WTk; Kd = 128; J = 128; tl = wb - 16; }
  else if (wb < 48) { src = Wv; dst = WTv; Kd = 128; J = 128; tl = wb - 32; }
  else if (wb < 64) { src = Wp; dst = WTp; Kd = 128; J = 128; tl = wb - 48; }
  else if (wb < 96) { src = W1; dst = WT1; Kd = 128; J = 256; tl = wb - 64; }
  else              { src = W2; dst = WT2; Kd = 256; J = 128; tl = wb - 96; }
  const int njt = J >> 5;
  const int tj = tl % njt, tk = tl / njt;
#pragma unroll
  for (int i = 0; i < 4; ++i) {
    int idx = t + 256 * i;
    int r = idx >> 5, c = idx & 31;
    tile[r][c] = src[(size_t)(tk * 32 + r) * J + tj * 32 + c];
  }
  __syncthreads();
#pragma unroll
  for (int i = 0; i < 2; ++i) {
    int idx = t + 256 * i;               // 512 pairs
    int rr = idx >> 4, c2 = (idx & 15) << 1;
    *(unsigned*)&dst[(size_t)(tj * 32 + rr) * Kd + tk * 32 + c2] =
        pkbf(tile[c2][rr], tile[c2 + 1][rr]);
  }
}

// ---------------------------------------------------------------------------
// Kernel A: fused q/k/v LN + MFMA projection (single dispatch, 1296 blocks).
// blocks [0,864): q -> QPh (row-major, *SCALE); [864,1080): k -> KPh;
// [1080,1296): v -> VPTh transposed [b][h][dh][NK].
// ---------------------------------------------------------------------------
__global__ __launch_bounds__(256) void k_ln_proj_all(
    const float* __restrict__ qin, const float* __restrict__ kin,
    const float* __restrict__ vin,
    const float* __restrict__ lnq_g, const float* __restrict__ lnq_b,
    const float* __restrict__ lnk_g, const float* __restrict__ lnk_b,
    const float* __restrict__ lnv_g, const float* __restrict__ lnv_b,
    const unsigned short* __restrict__ WTq, const unsigned short* __restrict__ WTk,
    const unsigned short* __restrict__ WTv,
    const float* __restrict__ bq, const float* __restrict__ bk,
    const float* __restrict__ bv,
    unsigned short* __restrict__ QPh, unsigned short* __restrict__ KPh,
    unsigned short* __restrict__ VPTh)
{
  __shared__ float xs[32][132];
  __shared__ unsigned short xh[32][136];
  __shared__ float gs[128], bs[128];
  __shared__ float mu[32], rsd[32];
  const int t = threadIdx.x;
  const int bid = blockIdx.x;

  const float* x; const unsigned short* WT; const float* g; const float* bl;
  const float* bias; int S, blk, mode; float osc;
  if (bid < 864)       { mode = 0; blk = bid;        x = qin; WT = WTq; g = lnq_g; bl = lnq_b; bias = bq; S = Q_; osc = SCALE_; }
  else if (bid < 1080) { mode = 0; blk = bid - 864;  x = kin; WT = WTk; g = lnk_g; bl = lnk_b; bias = bk; S = K_; osc = 1.0f; }
  else                 { mode = 1; blk = bid - 1080; x = vin; WT = WTv; g = lnv_g; bl = lnv_b; bias = bv; S = K_; osc = 1.0f; }
  const int ntile = S >> 5;
  const int o  = blk / ntile;
  const int s0 = (blk % ntile) << 5;

  if (t < 128) { gs[t] = g[t]; bs[t] = bl[t]; }
  const float* xb = x + (size_t)o * 128 * (size_t)S + s0;
  // float4 staging: 1024 vec4 loads cover the 128x32 tile
#pragma unroll
  for (int i = 0; i < 4; ++i) {
    int idx = t + 256 * i;
    int c = idx >> 3, s4 = (idx & 7) << 2;
    float4 xv = *(const float4*)&xb[(size_t)c * S + s4];
    xs[s4 + 0][c] = xv.x; xs[s4 + 1][c] = xv.y;
    xs[s4 + 2][c] = xv.z; xs[s4 + 3][c] = xv.w;
  }
  __syncthreads();
  {
    int s = t >> 3, l8 = t & 7;
    float sum = 0.f, sq = 0.f;
    for (int c = l8; c < 128; c += 8) { float v = xs[s][c]; sum += v; sq += v * v; }
#pragma unroll
    for (int off = 4; off > 0; off >>= 1) {
      sum += __shfl_down(sum, off, 8);
      sq  += __shfl_down(sq,  off, 8);
    }
    if (l8 == 0) {
      float mth = sum * 0.0078125f;
      float var = sq * 0.0078125f - mth * mth;
      mu[s] = mth; rsd[s] = rsqrtf(var + 1e-5f);
    }
  }
  __syncthreads();
#pragma unroll
  for (int i = 0; i < 8; ++i) {
    int idx = t + 256 * i;               // 2048 pairs
    int s = idx >> 6, c2 = (idx & 63) << 1;
    float y0 = (xs[s][c2]     - mu[s]) * rsd[s] * gs[c2]     + bs[c2];
    float y1 = (xs[s][c2 + 1] - mu[s]) * rsd[s] * gs[c2 + 1] + bs[c2 + 1];
    *(unsigned*)&xh[s][c2] = pkbf(y0, y1);
  }
  __syncthreads();
  const int w = t >> 6, lane = t & 63, quad = lane >> 4, l16 = lane & 15;
  const f32x4 zf = {0.f, 0.f, 0.f, 0.f};
  f32x4 acc[2][2] = {{zf, zf}, {zf, zf}};
#pragma unroll
  for (int kc = 0; kc < 4; ++kc) {
    bf16x8 a0 = *(const bf16x8*)&xh[l16][kc * 32 + quad * 8];
    bf16x8 a1 = *(const bf16x8*)&xh[16 + l16][kc * 32 + quad * 8];
    bf16x8 b0 = *(const bf16x8*)&WT[(size_t)(w * 32 + l16) * 128 + kc * 32 + quad * 8];
    bf16x8 b1 = *(const bf16x8*)&WT[(size_t)(w * 32 + 16 + l16) * 128 + kc * 32 + quad * 8];
    acc[0][0] = __builtin_amdgcn_mfma_f32_16x16x32_bf16(a0, b0, acc[0][0], 0, 0, 0);
    acc[0][1] = __builtin_amdgcn_mfma_f32_16x16x32_bf16(a0, b1, acc[0][1], 0, 0, 0);
    acc[1][0] = __builtin_amdgcn_mfma_f32_16x16x32_bf16(a1, b0, acc[1][0], 0, 0, 0);
    acc[1][1] = __builtin_amdgcn_mfma_f32_16x16x32_bf16(a1, b1, acc[1][1], 0, 0, 0);
  }
  if (mode == 0) {
    unsigned short* outh = (bid < 864) ? QPh : KPh;
    __syncthreads();                      // xh reused as output staging
#pragma unroll
    for (int mt = 0; mt < 2; ++mt)
#pragma unroll
      for (int nt = 0; nt < 2; ++nt) {
        int col = w * 32 + nt * 16 + l16;
        float bc = bias[col];
#pragma unroll
        for (int r = 0; r < 4; ++r)
          xh[mt * 16 + quad * 4 + r][col] = f2bf((acc[mt][nt][r] + bc) * osc);
      }
    __syncthreads();
#pragma unroll
    for (int i = 0; i < 2; ++i) {
      int s = i * 16 + (t >> 4), c8 = (t & 15) << 3;
      *(uint4*)&outh[((size_t)o * S + s0 + s) * 128 + c8] = *(uint4*)&xh[s][c8];
    }
  } else {
    const int b = o / 6, n = o % 6;
#pragma unroll
    for (int mt = 0; mt < 2; ++mt)
#pragma unroll
      for (int nt = 0; nt < 2; ++nt) {
        int col = w * 32 + nt * 16 + l16;
        int hh = col >> 5, dh = col & 31;
        float bc = bias[col];
        ushort4 pk;
        pk.x = f2bf(acc[mt][nt][0] + bc); pk.y = f2bf(acc[mt][nt][1] + bc);
        pk.z = f2bf(acc[mt][nt][2] + bc); pk.w = f2bf(acc[mt][nt][3] + bc);
        int s = n * 576 + s0 + mt * 16 + quad * 4;
        *(ushort4*)&VPTh[((size_t)(b * 4 + hh) * 32 + dh) * (size_t)NK_ + s] = pk;
      }
  }
}

// ---------------------------------------------------------------------------
// Kernel B: MFMA flash attention, no-max softmax, split-K 4-WAY,
// two q-tiles per wave. LDS epilogue buffer aliases the P buffer (12.3 KB
// total -> residency is wave-limited). Grid: 72 qpos x 8 bh x 4 ks = 2304.
// ---------------------------------------------------------------------------
__global__ __launch_bounds__(256) void k_attn_mfma(
    const unsigned short* __restrict__ QPh, const unsigned short* __restrict__ KPh,
    const unsigned short* __restrict__ VPTh, float* __restrict__ PO,
    float* __restrict__ Pl)
{
  __shared__ __align__(16) char smem_u[10240];   // plds (10240 B) / ol (8192 B)
  unsigned short (*plds)[2][16][40] = (unsigned short (*)[2][16][40])smem_u;
  float (*ol)[16][32] = (float (*)[16][32])smem_u;
  __shared__ float ll[4][2][4][16];
  const int t = threadIdx.x;
  const int w = t >> 6, lane = t & 63;
  const int quad = lane >> 4, l16 = lane & 15;
  const int qt = blockIdx.x % 72;
  const int rest = blockIdx.x / 72;            // 0..31
  const int bhx = rest >> 2, ks = rest & 3;
  const int bb = bhx >> 2, h = bhx & 3;
  const int q0 = qt << 5;

  const unsigned short* vbase = VPTh + (size_t)bhx * 32 * (size_t)NK_;
  const f32x4 zf = {0.f, 0.f, 0.f, 0.f};
  f32x4 o00 = zf, o01 = zf, o10 = zf, o11 = zf;
  float lsum0 = 0.f, lsum1 = 0.f;

  const int m16 = ks * 4 + w;
  int c0 = (108 * m16) >> 4, c1 = (108 * (m16 + 1)) >> 4;   // 6-7 chunks

  while (c0 < c1) {
    const int nn = c0 / 18;
    const int cend = min(c1, (nn + 1) * 18);
    const unsigned short* kb = &KPh[((size_t)(bb * 6 + nn) * K_) * 128 + h * 32];
    const unsigned short* qb = &QPh[((size_t)(bb * 6 + nn) * Q_ + q0) * 128 + h * 32];
    bf16x8 qc0 = *(const bf16x8*)&qb[(size_t)l16 * 128 + quad * 8];
    bf16x8 qc1 = *(const bf16x8*)&qb[(size_t)(16 + l16) * 128 + quad * 8];

    int kl = (c0 - nn * 18) << 5;
    bf16x8 kf0 = *(const bf16x8*)&kb[(size_t)(kl + l16) * 128 + quad * 8];
    bf16x8 kf1 = *(const bf16x8*)&kb[(size_t)(kl + 16 + l16) * 128 + quad * 8];
    const unsigned short* vb = vbase + ((size_t)c0 << 5);
    bf16x8 vf0 = *(const bf16x8*)&vb[(size_t)l16 * NK_ + quad * 8];
    bf16x8 vf1 = *(const bf16x8*)&vb[(size_t)(16 + l16) * NK_ + quad * 8];

    for (int kc = c0; kc < cend; ++kc) {
      const int kn = (kc + 1 < cend) ? kc + 1 : kc;
      const int kln = (kn - nn * 18) << 5;
      bf16x8 nk0 = *(const bf16x8*)&kb[(size_t)(kln + l16) * 128 + quad * 8];
      bf16x8 nk1 = *(const bf16x8*)&kb[(size_t)(kln + 16 + l16) * 128 + quad * 8];
      const unsigned short* vbn = vbase + ((size_t)kn << 5);
      bf16x8 nv0 = *(const bf16x8*)&vbn[(size_t)l16 * NK_ + quad * 8];
      bf16x8 nv1 = *(const bf16x8*)&vbn[(size_t)(16 + l16) * NK_ + quad * 8];

      // S^T tiles for both q-tiles (shared K fragments)
      f32x4 s00 = __builtin_amdgcn_mfma_f32_16x16x32_bf16(kf0, qc0, zf, 0, 0, 0);
      f32x4 s01 = __builtin_amdgcn_mfma_f32_16x16x32_bf16(kf1, qc0, zf, 0, 0, 0);
      f32x4 s10 = __builtin_amdgcn_mfma_f32_16x16x32_bf16(kf0, qc1, zf, 0, 0, 0);
      f32x4 s11 = __builtin_amdgcn_mfma_f32_16x16x32_bf16(kf1, qc1, zf, 0, 0, 0);

      float a00 = __expf(fminf(s00.x, 70.f)), a01 = __expf(fminf(s00.y, 70.f));
      float a02 = __expf(fminf(s00.z, 70.f)), a03 = __expf(fminf(s00.w, 70.f));
      float a10 = __expf(fminf(s01.x, 70.f)), a11 = __expf(fminf(s01.y, 70.f));
      float a12 = __expf(fminf(s01.z, 70.f)), a13 = __expf(fminf(s01.w, 70.f));
      lsum0 += (a00 + a01 + a02 + a03) + (a10 + a11 + a12 + a13);
      float b00 = __expf(fminf(s10.x, 70.f)), b01 = __expf(fminf(s10.y, 70.f));
      float b02 = __expf(fminf(s10.z, 70.f)), b03 = __expf(fminf(s10.w, 70.f));
      float b10 = __expf(fminf(s11.x, 70.f)), b11 = __expf(fminf(s11.y, 70.f));
      float b12 = __expf(fminf(s11.z, 70.f)), b13 = __expf(fminf(s11.w, 70.f));
      lsum1 += (b00 + b01 + b02 + b03) + (b10 + b11 + b12 + b13);

      // packed b64 LDS writes (2 per tile)
      uint2 w0a; w0a.x = pkbf(a00, a01); w0a.y = pkbf(a02, a03);
      uint2 w0b; w0b.x = pkbf(a10, a11); w0b.y = pkbf(a12, a13);
      uint2 w1a; w1a.x = pkbf(b00, b01); w1a.y = pkbf(b02, b03);
      uint2 w1b; w1b.x = pkbf(b10, b11); w1b.y = pkbf(b12, b13);
      *(uint2*)&plds[w][0][l16][quad * 4]      = w0a;
      *(uint2*)&plds[w][0][l16][16 + quad * 4] = w0b;
      *(uint2*)&plds[w][1][l16][quad * 4]      = w1a;
      *(uint2*)&plds[w][1][l16][16 + quad * 4] = w1b;
      bf16x8 pf0 = *(const bf16x8*)&plds[w][0][l16][quad * 8];
      bf16x8 pf1 = *(const bf16x8*)&plds[w][1][l16][quad * 8];

      o00 = __builtin_amdgcn_mfma_f32_16x16x32_bf16(pf0, vf0, o00, 0, 0, 0);
      o01 = __builtin_amdgcn_mfma_f32_16x16x32_bf16(pf0, vf1, o01, 0, 0, 0);
      o10 = __builtin_amdgcn_mfma_f32_16x16x32_bf16(pf1, vf0, o10, 0, 0, 0);
      o11 = __builtin_amdgcn_mfma_f32_16x16x32_bf16(pf1, vf1, o11, 0, 0, 0);

      kf0 = nk0; kf1 = nk1; vf0 = nv0; vf1 = nv1;
    }
    c0 = cend;
  }

  ll[w][0][quad][l16] = lsum0;      // ll is NOT aliased; safe pre-barrier
  ll[w][1][quad][l16] = lsum1;
#pragma unroll
  for (int tt = 0; tt < 2; ++tt) {
    __syncthreads();                 // first iter: all waves done with plds
    f32x4 t0 = tt ? o10 : o00;
    f32x4 t1 = tt ? o11 : o01;
#pragma unroll
    for (int r = 0; r < 4; ++r) {
      ol[w][quad * 4 + r][l16]      = t0[r];
      ol[w][quad * 4 + r][16 + l16] = t1[r];
    }
    __syncthreads();
    const int q = t >> 4, i16 = t & 15, dd = i16 << 1;
    float a0 = 0.f, a1 = 0.f;
#pragma unroll
    for (int ww = 0; ww < 4; ++ww) { a0 += ol[ww][q][dd]; a1 += ol[ww][q][dd + 1]; }
    float2 r2; r2.x = a0; r2.y = a1;
    *(float2*)&PO[(((size_t)ks * 8 + bhx) * Q_ + q0 + tt * 16 + q) * 32 + dd] = r2;
    if (i16 == 0) {
      float l = 0.f;
#pragma unroll
      for (int ww = 0; ww < 4; ++ww)
#pragma unroll
        for (int qq = 0; qq < 4; ++qq) l += ll[ww][tt][qq][q];
      Pl[((size_t)ks * 8 + bhx) * Q_ + q0 + tt * 16 + q] = l;
    }
  }
}

// ---------------------------------------------------------------------------
// Kernel C (fused tail, 512 threads): 4-way ksplit-merge + out-proj + skip
// + preLN + fc1 + GELU + fc2 + residual + postLN + transposed store.
// 8 waves split each MFMA stage's columns. 144 blocks x 32 rows.
// ---------------------------------------------------------------------------
__global__ __launch_bounds__(512) void k_tail(
    const float* __restrict__ PO, const float* __restrict__ Pl,
    const unsigned short* __restrict__ WTp, const float* __restrict__ bp,
    const float* __restrict__ skip,
    const float* __restrict__ pre_g, const float* __restrict__ pre_b,
    const unsigned short* __restrict__ WT1, const float* __restrict__ b1,
    const unsigned short* __restrict__ WT2, const float* __restrict__ b2,
    const float* __restrict__ post_g, const float* __restrict__ post_b,
    float* __restrict__ out)
{
  __shared__ float xs[32][132];
  __shared__ unsigned short xh[32][136];
  __shared__ unsigned short hb[32][264];
  __shared__ float g1s[128], b1s[128], g2s[128], b2s[128];
  __shared__ float mu[32], rsd[32];
  const int t = threadIdx.x;
  const int row0 = blockIdx.x << 5;
  const int bb = row0 / Q_, hw0 = row0 % Q_;
  const int w = t >> 6, lane = t & 63, quad = lane >> 4, l16 = lane & 15;
  const f32x4 zf = {0.f, 0.f, 0.f, 0.f};

  if (t < 128) { g1s[t] = pre_g[t]; b1s[t] = pre_b[t]; g2s[t] = post_g[t]; b2s[t] = post_b[t]; }
  // --- stage 1: merge 4-way ksplit partials -> bf16 A-frags in xh
#pragma unroll
  for (int i = 0; i < 4; ++i) {
    int idx = t + 512 * i;               // 2048 pairs
    int s = idx >> 6, c2 = (idx & 63) << 1;
    int q = hw0 + s;
    int h = c2 >> 5, dh = c2 & 31;
    size_t bq = (size_t)(bb * 4 + h) * Q_ + q;
    size_t i0 = bq * 32 + dh;
    float o0 = 0.f, o1 = 0.f, l = 0.f;
#pragma unroll
    for (int p = 0; p < 4; ++p) {
      float2 pp = *(const float2*)&PO[(size_t)p * 589824 + i0];
      o0 += pp.x; o1 += pp.y;
      l  += Pl[(size_t)p * 18432 + bq];
    }
    float inv = 1.f / l;
    *(unsigned*)&xh[s][c2] = pkbf(o0 * inv, o1 * inv);
  }
  __syncthreads();
  // --- stage 2: out-projection MFMA (wave w: cols w*16..w*16+15)
  {
    f32x4 acc[2] = {zf, zf};
    const int col = w * 16 + l16;
#pragma unroll
    for (int kc = 0; kc < 4; ++kc) {
      bf16x8 a0 = *(const bf16x8*)&xh[l16][kc * 32 + quad * 8];
      bf16x8 a1 = *(const bf16x8*)&xh[16 + l16][kc * 32 + quad * 8];
      bf16x8 b0 = *(const bf16x8*)&WTp[(size_t)col * 128 + kc * 32 + quad * 8];
      acc[0] = __builtin_amdgcn_mfma_f32_16x16x32_bf16(a0, b0, acc[0], 0, 0, 0);
      acc[1] = __builtin_amdgcn_mfma_f32_16x16x32_bf16(a1, b0, acc[1], 0, 0, 0);
    }
    float bc = bp[col];
#pragma unroll
    for (int mt = 0; mt < 2; ++mt) {
      float4 sk = *(const float4*)&skip[((size_t)bb * 128 + col) * Q_ + hw0 + mt * 16 + quad * 4];
      xs[mt * 16 + quad * 4 + 0][col] = acc[mt][0] + bc + sk.x;
      xs[mt * 16 + quad * 4 + 1][col] = acc[mt][1] + bc + sk.y;
      xs[mt * 16 + quad * 4 + 2][col] = acc[mt][2] + bc + sk.z;
      xs[mt * 16 + quad * 4 + 3][col] = acc[mt][3] + bc + sk.w;
    }
  }
  __syncthreads();
  // --- stage 3: preLN (16 lanes per row)
  {
    int s = t >> 4, lg = t & 15;
    float sum = 0.f, sq = 0.f;
    for (int c = lg; c < 128; c += 16) { float v = xs[s][c]; sum += v; sq += v * v; }
#pragma unroll
    for (int off = 8; off > 0; off >>= 1) {
      sum += __shfl_down(sum, off, 16);
      sq  += __shfl_down(sq,  off, 16);
    }
    if (lg == 0) {
      float mth = sum * 0.0078125f;
      float var = sq * 0.0078125f - mth * mth;
      mu[s] = mth; rsd[s] = rsqrtf(var + 1e-5f);
    }
  }
  __syncthreads();
#pragma unroll
  for (int i = 0; i < 4; ++i) {
    int idx = t + 512 * i;
    int s = idx >> 6, c2 = (idx & 63) << 1;
    float y0 = (xs[s][c2]     - mu[s]) * rsd[s] * g1s[c2]     + b1s[c2];
    float y1 = (xs[s][c2 + 1] - mu[s]) * rsd[s] * g1s[c2 + 1] + b1s[c2 + 1];
    xs[s][c2] = y0; xs[s][c2 + 1] = y1;
    *(unsigned*)&xh[s][c2] = pkbf(y0, y1);
  }
  __syncthreads();
  // --- stage 4: fc1 + GELU (wave w: cols w*32..w*32+31 of 256)
  {
#pragma unroll
    for (int nt = 0; nt < 2; ++nt) {
      const int col = w * 32 + nt * 16 + l16;
      f32x4 acc[2] = {zf, zf};
#pragma unroll
      for (int kc = 0; kc < 4; ++kc) {
        bf16x8 a0 = *(const bf16x8*)&xh[l16][kc * 32 + quad * 8];
        bf16x8 a1 = *(const bf16x8*)&xh[16 + l16][kc * 32 + quad * 8];
        bf16x8 b0 = *(const bf16x8*)&WT1[(size_t)col * 128 + kc * 32 + quad * 8];
        acc[0] = __builtin_amdgcn_mfma_f32_16x16x32_bf16(a0, b0, acc[0], 0, 0, 0);
        acc[1] = __builtin_amdgcn_mfma_f32_16x16x32_bf16(a1, b0, acc[1], 0, 0, 0);
      }
      float bc = b1[col];
#pragma unroll
      for (int mt = 0; mt < 2; ++mt)
#pragma unroll
        for (int r = 0; r < 4; ++r) {
          float hx = acc[mt][r] + bc;
          hb[mt * 16 + quad * 4 + r][col] =
              f2bf(0.5f * hx * (1.f + erff(hx * 0.7071067811865476f)));
        }
    }
  }
  __syncthreads();
  // --- stage 5: fc2 (K=256) + residual z (wave w: cols w*16..w*16+15)
  {
    f32x4 acc[2] = {zf, zf};
    const int col = w * 16 + l16;
#pragma unroll
    for (int kc = 0; kc < 8; ++kc) {
      bf16x8 a0 = *(const bf16x8*)&hb[l16][kc * 32 + quad * 8];
      bf16x8 a1 = *(const bf16x8*)&hb[16 + l16][kc * 32 + quad * 8];
      bf16x8 b0 = *(const bf16x8*)&WT2[(size_t)col * 256 + kc * 32 + quad * 8];
      acc[0] = __builtin_amdgcn_mfma_f32_16x16x32_bf16(a0, b0, acc[0], 0, 0, 0);
      acc[1] = __builtin_amdgcn_mfma_f32_16x16x32_bf16(a1, b0, acc[1], 0, 0, 0);
    }
    float bc = b2[col];
#pragma unroll
    for (int mt = 0; mt < 2; ++mt)
#pragma unroll
      for (int r = 0; r < 4; ++r) {
        int row = mt * 16 + quad * 4 + r;
        xs[row][col] = acc[mt][r] + bc + xs[row][col];
      }
  }
  __syncthreads();
  // --- stage 6: postLN + transposed store
  {
    int s = t >> 4, lg = t & 15;
    float sum = 0.f, sq = 0.f;
    for (int c = lg; c < 128; c += 16) { float v = xs[s][c]; sum += v; sq += v * v; }
#pragma unroll
    for (int off = 8; off > 0; off >>= 1) {
      sum += __shfl_down(sum, off, 16);
      sq  += __shfl_down(sq,  off, 16);
    }
    if (lg == 0) {
      float mth = sum * 0.0078125f;
      float var = sq * 0.0078125f - mth * mth;
      mu[s] = mth; rsd[s] = rsqrtf(var + 1e-5f);
    }
  }
  __syncthreads();
#pragma unroll
  for (int i = 0; i < 8; ++i) {
    int idx = t + 512 * i;
    int s = idx & 31, c = idx >> 5;
    out[(size_t)bb * (128 * (size_t)Q_) + (size_t)c * Q_ + hw0 + s] =
        (xs[s][c] - mu[s]) * rsd[s] * g2s[c] + b2s[c];
  }
}

// ---------------------------------------------------------------------------
extern "C" void kernel_launch(void* const* d_in, const int* in_sizes, int n_in,
                              void* d_out, int out_size, void* d_ws, size_t ws_size,
                              hipStream_t stream) {
  const float* q     = (const float*)d_in[0];
  const float* k     = (const float*)d_in[1];
  const float* v     = (const float*)d_in[2];
  const float* skip  = (const float*)d_in[3];
  const float* lnq_g = (const float*)d_in[4];
  const float* lnq_b = (const float*)d_in[5];
  const float* Wq    = (const float*)d_in[6];
  const float* bq    = (const float*)d_in[7];
  const float* lnk_g = (const float*)d_in[8];
  const float* lnk_b = (const float*)d_in[9];
  const float* Wk    = (const float*)d_in[10];
  const float* bk    = (const float*)d_in[11];
  const float* lnv_g = (const float*)d_in[12];
  const float* lnv_b = (const float*)d_in[13];
  const float* Wv    = (const float*)d_in[14];
  const float* bvv   = (const float*)d_in[15];
  const float* Wp    = (const float*)d_in[16];
  const float* bp    = (const float*)d_in[17];
  const float* pre_g = (const float*)d_in[18];
  const float* pre_b = (const float*)d_in[19];
  const float* W1    = (const float*)d_in[20];
  const float* b1    = (const float*)d_in[21];
  const float* W2    = (const float*)d_in[22];
  const float* b2    = (const float*)d_in[23];
  const float* post_g= (const float*)d_in[24];
  const float* post_b= (const float*)d_in[25];
  float* out = (float*)d_out;

  // Workspace layout (~21 MB)
  unsigned short* QPh  = (unsigned short*)d_ws;        // 3,538,944 h
  unsigned short* KPh  = QPh + 3538944;                //   884,736 h
  unsigned short* VPTh = KPh + 884736;                 //   884,736 h
  float* PO  = (float*)(VPTh + 884736);                // 2,359,296 f (4 partials)
  float* Pl  = PO + 2359296;                           //    73,728 f
  unsigned short* WTq = (unsigned short*)(Pl + 73728); //    16,384 h
  unsigned short* WTk = WTq + 16384;                   //    16,384 h
  unsigned short* WTv = WTk + 16384;                   //    16,384 h
  unsigned short* WTp = WTv + 16384;                   //    16,384 h
  unsigned short* WT1 = WTp + 16384;                   //    32,768 h
  unsigned short* WT2 = WT1 + 32768;                   //    32,768 h

  k_prep_wt<<<dim3(128), dim3(256), 0, stream>>>(Wq, Wk, Wv, Wp, W1, W2,
                                                 WTq, WTk, WTv, WTp, WT1, WT2);
  k_ln_proj_all<<<dim3(1296), dim3(256), 0, stream>>>(
      q, k, v, lnq_g, lnq_b, lnk_g, lnk_b, lnv_g, lnv_b,
      WTq, WTk, WTv, bq, bk, bvv, QPh, KPh, VPTh);
  k_attn_mfma<<<dim3(2304), dim3(256), 0, stream>>>(QPh, KPh, VPTh, PO, Pl);
  k_tail<<<dim3(144), dim3(512), 0, stream>>>(PO, Pl, WTp, bp, skip,
                                              pre_g, pre_b, WT1, b1, WT2, b2,
                                              post_g, post_b, out);
}